// Round 9
// baseline (244.417 us; speedup 1.0000x reference)
//
#include <hip/hip_runtime.h>
#include <hip/hip_bf16.h>

#define NN 65536
#define EE 1048576
#define BG 64
#define NPGC 1024
#define KKEEP 820

typedef unsigned short u16;
typedef unsigned int u32;
typedef __attribute__((ext_vector_type(4))) float f32x4;
typedef __attribute__((ext_vector_type(8))) short bf16x8;

__device__ __forceinline__ float bfu_lo(u32 u) {  // low bf16 -> f32
    u32 x = u << 16;
    return __builtin_bit_cast(float, x);
}
__device__ __forceinline__ float bfu_hi(u32 u) {  // high bf16 -> f32
    u32 x = u & 0xffff0000u;
    return __builtin_bit_cast(float, x);
}
__device__ __forceinline__ u16 fbf(float f) {
    __hip_bfloat16 h = __float2bfloat16(f);
    return __builtin_bit_cast(u16, h);
}
__device__ __forceinline__ u32 pack2(float a, float b) {
    return (u32)fbf(a) | ((u32)fbf(b) << 16);
}

// ---------------- CSR build + stable degree-sort order ----------------
// one block per graph: LDS histogram -> scan -> cursor fill -> rank-sort.
// nord[g*1024 + pos] = local node id, ordered by (deg asc, id asc). Waves in
// agg then get similar-degree nodes -> minimal divergence in the edge loop.
__global__ __launch_bounds__(1024) void csr_build_kernel(const int* __restrict__ src,
                                                         const int* __restrict__ dst,
                                                         int* __restrict__ noff,
                                                         int* __restrict__ deg,
                                                         int* __restrict__ csr,
                                                         int* __restrict__ nord) {
    __shared__ int hist[NPGC];
    __shared__ int scan[NPGC];
    int g = blockIdx.x, t = threadIdx.x;
    hist[t] = 0;
    __syncthreads();
    int ebase = g * 16384;
    for (int i = t; i < 16384; i += 1024) atomicAdd(&hist[dst[ebase + i] & 1023], 1);
    __syncthreads();
    int d = hist[t];
    scan[t] = d;
    __syncthreads();
    for (int s = 1; s < NPGC; s <<= 1) {
        int add = (t >= s) ? scan[t - s] : 0;
        __syncthreads();
        scan[t] += add;
        __syncthreads();
    }
    int excl = scan[t] - d;
    int node = g * NPGC + t;
    deg[node] = d;
    noff[node] = ebase + excl;
    hist[t] = excl;  // fill cursor
    __syncthreads();
    for (int i = t; i < 16384; i += 1024) {
        int dl = dst[ebase + i] & 1023;
        int p = atomicAdd(&hist[dl], 1);
        csr[ebase + p] = src[ebase + i];
    }
    // stable rank by (deg, id): deterministic permutation
    scan[t] = d;
    __syncthreads();
    int pos = 0;
#pragma unroll 4
    for (int m = 0; m < NPGC; ++m) {
        int dm = scan[m];
        pos += (dm < d || (dm == d && m < t)) ? 1 : 0;
    }
    nord[g * NPGC + pos] = t;
}

// WT[l][col][k]: 3 weight sets at once. l = blockIdx.y.
__global__ void prep_w_kernel(const float* __restrict__ Wr1, const float* __restrict__ Wo1,
                              const float* __restrict__ Wr2, const float* __restrict__ Wo2,
                              const float* __restrict__ Wr3, const float* __restrict__ Wo3,
                              u16* __restrict__ WT) {
    int l = blockIdx.y;
    const float* Wrel = l == 0 ? Wr1 : (l == 1 ? Wr2 : Wr3);
    const float* Wroot = l == 0 ? Wo1 : (l == 1 ? Wo2 : Wo3);
    int idx = blockIdx.x * 256 + threadIdx.x;  // 32768
    int col = idx >> 7, k = idx & 127;
    float v = (col < 128) ? Wrel[k * 128 + col] : Wroot[k * 128 + (col - 128)];
    WT[l * 32768 + idx] = fbf(v);
}

// ---------------- GEMM: Y[N][256] = A[N][128] @ Wcat[128][256]  (bf16 MFMA, fp32 acc)
// MODE 0: A = bf16 Xb.  MODE 1: A = fp32 Xf (cast fused, conv1).
// MODE 2: A = bf16 Xb * gate[row] (gate fused, conv3).
template <int MODE>
__global__ __launch_bounds__(256, 2) void gemm_kernel(const u16* __restrict__ Xb,
                                                      const float* __restrict__ Xf,
                                                      const float* __restrict__ gate,
                                                      const u16* __restrict__ WT,
                                                      u16* __restrict__ Y) {
    __shared__ u16 As[128][72];
    __shared__ u16 Bs[128][72];
    int rb = blockIdx.x * 128;
    int cb = blockIdx.y * 128;
    int tid = threadIdx.x;
    int lane = tid & 63, wid = tid >> 6;
    int wr = (wid >> 1) << 6, wc = (wid & 1) << 6;
    int lr = lane & 15, lk = (lane >> 4) << 3;
    f32x4 acc[4][4] = {};

    for (int half = 0; half < 2; ++half) {
        int k0 = half << 6;
        if (half) __syncthreads();
        for (int i = tid; i < 1024; i += 256) {
            int r = i >> 3, c = (i & 7) << 3;
            uint4 av;
            if (MODE == 0) {
                av = *reinterpret_cast<const uint4*>(Xb + (size_t)(rb + r) * 128 + k0 + c);
            } else if (MODE == 1) {
                float4 f0 = *reinterpret_cast<const float4*>(Xf + (size_t)(rb + r) * 128 + k0 + c);
                float4 f1 = *reinterpret_cast<const float4*>(Xf + (size_t)(rb + r) * 128 + k0 + c + 4);
                av.x = pack2(f0.x, f0.y);
                av.y = pack2(f0.z, f0.w);
                av.z = pack2(f1.x, f1.y);
                av.w = pack2(f1.z, f1.w);
            } else {
                float g = gate[rb + r];
                uint4 w = *reinterpret_cast<const uint4*>(Xb + (size_t)(rb + r) * 128 + k0 + c);
                av.x = pack2(bfu_lo(w.x) * g, bfu_hi(w.x) * g);
                av.y = pack2(bfu_lo(w.y) * g, bfu_hi(w.y) * g);
                av.z = pack2(bfu_lo(w.z) * g, bfu_hi(w.z) * g);
                av.w = pack2(bfu_lo(w.w) * g, bfu_hi(w.w) * g);
            }
            *reinterpret_cast<uint4*>(&As[r][c]) = av;
            *reinterpret_cast<uint4*>(&Bs[r][c]) =
                *reinterpret_cast<const uint4*>(WT + (cb + r) * 128 + k0 + c);
        }
        __syncthreads();
        for (int kk = 0; kk < 64; kk += 32) {
            bf16x8 a[4], b[4];
            for (int m = 0; m < 4; ++m)
                a[m] = *reinterpret_cast<const bf16x8*>(&As[wr + m * 16 + lr][kk + lk]);
            for (int n = 0; n < 4; ++n)
                b[n] = *reinterpret_cast<const bf16x8*>(&Bs[wc + n * 16 + lr][kk + lk]);
            for (int m = 0; m < 4; ++m)
                for (int n = 0; n < 4; ++n)
                    acc[m][n] = __builtin_amdgcn_mfma_f32_16x16x32_bf16(a[m], b[n], acc[m][n], 0, 0, 0);
        }
    }
    int orow0 = rb + wr + ((lane >> 4) << 2);
    int ocol0 = cb + wc + (lane & 15);
    for (int m = 0; m < 4; ++m)
        for (int n = 0; n < 4; ++n)
            for (int r = 0; r < 4; ++r)
                Y[(size_t)(orow0 + m * 16 + r) * 256 + ocol0 + n * 16] = fbf(acc[m][n][r]);
}

// ---------------- LDS-staged aggregate + combine + relu + pool (+score) ----------------
// Block = (graph, 32-feature chunk). Stage all 1024 rel-rows' chunk into LDS
// feature-major (sst[fp][node], u32 = 2 bf16). Thread t owns node nord[t]
// (degree-sorted => wave-uniform edge loops) and accumulates via LDS reads.
// Pool per (graph,chunk) is exclusive -> plain stores, no atomics.
// LAYER 0: conv1 (outb). LAYER 1: conv2 (outb + score partials). LAYER 2: conv3 (keep/cnt).
template <int LAYER>
__global__ __launch_bounds__(1024, 4) void agg_kernel(const u16* __restrict__ Y,
                                                      const int* __restrict__ csr,
                                                      const int* __restrict__ noff,
                                                      const int* __restrict__ deg,
                                                      const int* __restrict__ nord,
                                                      const float* __restrict__ bias,
                                                      const float* __restrict__ keep,
                                                      const float* __restrict__ cntg,
                                                      u16* __restrict__ outb,
                                                      const float* __restrict__ wsrel,
                                                      const float* __restrict__ wsroot,
                                                      float* __restrict__ srelp,
                                                      float* __restrict__ srootp,
                                                      float* __restrict__ xs,
                                                      int base, float invdenom) {
    __shared__ u32 sst[16 * 1024];
    __shared__ float pool2[32 * 33];
    int g = blockIdx.x >> 2, c = blockIdx.x & 3;
    int t = threadIdx.x;
    int nbase = g * NPGC;

    // stage: thread t loads node t's 64B chunk (one cache line) -> 16 b32 LDS writes
    {
        const uint4* sp = reinterpret_cast<const uint4*>(Y + (size_t)(nbase + t) * 256 + c * 32);
        uint4 q0 = sp[0], q1 = sp[1], q2 = sp[2], q3 = sp[3];
        sst[0 * 1024 + t] = q0.x;  sst[1 * 1024 + t] = q0.y;
        sst[2 * 1024 + t] = q0.z;  sst[3 * 1024 + t] = q0.w;
        sst[4 * 1024 + t] = q1.x;  sst[5 * 1024 + t] = q1.y;
        sst[6 * 1024 + t] = q1.z;  sst[7 * 1024 + t] = q1.w;
        sst[8 * 1024 + t] = q2.x;  sst[9 * 1024 + t] = q2.y;
        sst[10 * 1024 + t] = q2.z; sst[11 * 1024 + t] = q2.w;
        sst[12 * 1024 + t] = q3.x; sst[13 * 1024 + t] = q3.y;
        sst[14 * 1024 + t] = q3.z; sst[15 * 1024 + t] = q3.w;
    }

    int nloc = nord[nbase + t];
    int node = nbase + nloc;
    int off = noff[node], dg = deg[node];
    float ki = 1.f, cnt;
    if (LAYER == 2) {
        ki = keep[node];
        cnt = cntg[node];
    } else {
        cnt = (float)dg;
    }
    __syncthreads();

    float accL[16] = {0.f, 0.f, 0.f, 0.f, 0.f, 0.f, 0.f, 0.f,
                      0.f, 0.f, 0.f, 0.f, 0.f, 0.f, 0.f, 0.f};
    float accH[16] = {0.f, 0.f, 0.f, 0.f, 0.f, 0.f, 0.f, 0.f,
                      0.f, 0.f, 0.f, 0.f, 0.f, 0.f, 0.f, 0.f};
    if (LAYER != 2 || ki != 0.f) {
        int nbr = (dg > 0) ? (csr[off] & 1023) : 0;
        for (int e = 0; e < dg; ++e) {
            int nxt = (e + 1 < dg) ? (csr[off + e + 1] & 1023) : 0;
#pragma unroll
            for (int fp = 0; fp < 16; ++fp) {
                u32 v = sst[fp * 1024 + nbr];
                accL[fp] += bfu_lo(v);
                accH[fp] += bfu_hi(v);
            }
            nbr = nxt;
        }
    }

    float inv = ki / fmaxf(cnt, 1.f);
    const uint4* rp = reinterpret_cast<const uint4*>(Y + (size_t)node * 256 + 128 + c * 32);
    uint4 r0 = rp[0], r1 = rp[1], r2 = rp[2], r3 = rp[3];
    u32 rr[16] = {r0.x, r0.y, r0.z, r0.w, r1.x, r1.y, r1.z, r1.w,
                  r2.x, r2.y, r2.z, r2.w, r3.x, r3.y, r3.z, r3.w};
    u32 pk[16];
    float pr = 0.f, po = 0.f;
#pragma unroll
    for (int fp = 0; fp < 16; ++fp) {
        float lo = fmaxf(accL[fp] * inv + bias[c * 32 + 2 * fp] + bfu_lo(rr[fp]), 0.f) * ki;
        float hi = fmaxf(accH[fp] * inv + bias[c * 32 + 2 * fp + 1] + bfu_hi(rr[fp]), 0.f) * ki;
        if (LAYER == 1) {
            pr += lo * wsrel[c * 32 + 2 * fp] + hi * wsrel[c * 32 + 2 * fp + 1];
            po += lo * wsroot[c * 32 + 2 * fp] + hi * wsroot[c * 32 + 2 * fp + 1];
        }
        pk[fp] = pack2(lo, hi);
    }
    if (LAYER != 2) {
        uint4* op = reinterpret_cast<uint4*>(outb + (size_t)node * 128 + c * 32);
        uint4 o0 = {pk[0], pk[1], pk[2], pk[3]};
        uint4 o1 = {pk[4], pk[5], pk[6], pk[7]};
        uint4 o2 = {pk[8], pk[9], pk[10], pk[11]};
        uint4 o3 = {pk[12], pk[13], pk[14], pk[15]};
        op[0] = o0; op[1] = o1; op[2] = o2; op[3] = o3;
    }
    if (LAYER == 1) {
        srelp[(size_t)c * NN + node] = pr;
        srootp[(size_t)c * NN + node] = po;
    }

    __syncthreads();  // all LDS gathers done; reuse sst for pool values
#pragma unroll
    for (int fp = 0; fp < 16; ++fp) sst[fp * 1024 + t] = pk[fp];
    __syncthreads();

    // pool reduce: f = feature in chunk, sub = node class mod 32
    {
        int f = t >> 5, sub = t & 31;
        float s = 0.f;
#pragma unroll 4
        for (int k = 0; k < 32; ++k) {
            u32 v = sst[(f >> 1) * 1024 + sub + 32 * k];
            s += (f & 1) ? bfu_hi(v) : bfu_lo(v);
        }
        pool2[f * 33 + sub] = s;
    }
    __syncthreads();
    if (t < 32) {
        float s = 0.f;
#pragma unroll 4
        for (int sub = 0; sub < 32; ++sub) s += pool2[t * 33 + sub];
        xs[g * 384 + base + c * 32 + t] = s * invdenom;
    }
}

// ---------------- per-graph top-K (score sum + bitonic sort + keep-count) ----------------
__global__ __launch_bounds__(1024) void topk_kernel(const float* __restrict__ srelp,
                                                    const float* __restrict__ srootp,
                                                    const float* __restrict__ bs,
                                                    const int* __restrict__ csr,
                                                    const int* __restrict__ noff,
                                                    const int* __restrict__ deg,
                                                    float* __restrict__ keep,
                                                    float* __restrict__ gate,
                                                    float* __restrict__ cntg) {
    __shared__ float sc[NPGC];
    __shared__ int si[NPGC];
    __shared__ float ssr[NPGC];
    int g = blockIdx.x, t = threadIdx.x;
    int node = g * NPGC + t;
    // fixed-order sum of the 4 chunk partials (deterministic)
    ssr[t] = srelp[node] + srelp[NN + node] + srelp[2 * NN + node] + srelp[3 * NN + node];
    float sroot = srootp[node] + srootp[NN + node] + srootp[2 * NN + node] + srootp[3 * NN + node];
    __syncthreads();
    int off = noff[node], dg = deg[node];
    float s = 0.f;
    for (int e = 0; e < dg; ++e) s += ssr[csr[off + e] & 1023];
    sc[t] = s / fmaxf((float)dg, 1.0f) + bs[0] + sroot;
    si[t] = t;
    __syncthreads();
    for (int k = 2; k <= NPGC; k <<= 1) {
        for (int j = k >> 1; j > 0; j >>= 1) {
            int ixj = t ^ j;
            if (ixj > t) {
                float a = sc[t], b = sc[ixj];
                int ai = si[t], bi = si[ixj];
                bool less = (a > b) || (a == b && ai < bi);  // desc, idx-asc tiebreak
                bool up = ((t & k) == 0);
                if (less != up) { sc[t] = b; sc[ixj] = a; si[t] = bi; si[ixj] = ai; }
            }
            __syncthreads();
        }
    }
    int oloc = si[t];
    float kf = (t < KKEEP) ? 1.f : 0.f;
    keep[g * NPGC + oloc] = kf;
    gate[g * NPGC + oloc] = kf * tanhf(sc[t]);
    ssr[oloc] = kf;  // reuse as keep flags
    __syncthreads();
    // conv3 neighbor keep-count
    float cnt = 0.f;
    for (int e = 0; e < dg; ++e) cnt += ssr[csr[off + e] & 1023];
    cntg[node] = cnt;
}

// ---------------- MLP head + log_softmax; one block of 512 per graph.
__global__ __launch_bounds__(512) void mlp_kernel(const float* __restrict__ xs,
                                                  const float* __restrict__ Wl1,
                                                  const float* __restrict__ bl1,
                                                  const float* __restrict__ Wl2,
                                                  const float* __restrict__ bl2,
                                                  float* __restrict__ out) {
    __shared__ float xsl[384];
    __shared__ float part[4][128];
    __shared__ float wl2s[1280];
    __shared__ float wred[2][10];
    __shared__ float lgs[10];
    int g = blockIdx.x, tid = threadIdx.x;
    int t = tid & 127, kg = tid >> 7;

    for (int i = tid; i < 1280; i += 512) wl2s[i] = Wl2[i];
    if (tid < 384) xsl[tid] = xs[g * 384 + tid];
    __syncthreads();

    float p = 0.f;
    int k0 = kg * 96;
#pragma unroll 8
    for (int k = 0; k < 96; ++k) p += xsl[k0 + k] * Wl1[(k0 + k) * 128 + t];
    part[kg][t] = p;
    __syncthreads();

    if (tid < 128) {
        float h = fmaxf(bl1[t] + part[0][t] + part[1][t] + part[2][t] + part[3][t], 0.f);
        float pc[10];
#pragma unroll
        for (int c = 0; c < 10; ++c) pc[c] = h * wl2s[t * 10 + c];
#pragma unroll
        for (int d = 1; d < 64; d <<= 1) {
#pragma unroll
            for (int c = 0; c < 10; ++c) pc[c] += __shfl_xor(pc[c], d, 64);
        }
        if ((t & 63) == 0) {
#pragma unroll
            for (int c = 0; c < 10; ++c) wred[t >> 6][c] = pc[c];
        }
    }
    __syncthreads();
    if (tid < 10) lgs[tid] = wred[0][tid] + wred[1][tid] + bl2[tid];
    __syncthreads();
    if (tid < 10) {
        float m = lgs[0];
#pragma unroll
        for (int c = 1; c < 10; ++c) m = fmaxf(m, lgs[c]);
        float s = 0.f;
#pragma unroll
        for (int c = 0; c < 10; ++c) s += expf(lgs[c] - m);
        out[g * 10 + tid] = lgs[tid] - m - logf(s);
    }
}

extern "C" void kernel_launch(void* const* d_in, const int* in_sizes, int n_in,
                              void* d_out, int out_size, void* d_ws, size_t ws_size,
                              hipStream_t stream) {
    const float* x       = (const float*)d_in[0];
    const int*   src     = (const int*)d_in[1];
    const int*   dst     = (const int*)d_in[2];
    const float* W1_rel  = (const float*)d_in[3];
    const float* b1      = (const float*)d_in[4];
    const float* W1_root = (const float*)d_in[5];
    const float* W2_rel  = (const float*)d_in[6];
    const float* b2      = (const float*)d_in[7];
    const float* W2_root = (const float*)d_in[8];
    const float* W3_rel  = (const float*)d_in[9];
    const float* b3      = (const float*)d_in[10];
    const float* W3_root = (const float*)d_in[11];
    const float* Ws_rel  = (const float*)d_in[12];
    const float* bs      = (const float*)d_in[13];
    const float* Ws_root = (const float*)d_in[14];
    const float* Wl1     = (const float*)d_in[15];
    const float* bl1     = (const float*)d_in[16];
    const float* Wl2     = (const float*)d_in[17];
    const float* bl2     = (const float*)d_in[18];

    char* ws = (char*)d_ws;
    size_t off = 0;
    auto alloc = [&](size_t bytes) -> void* {
        void* p = ws + off;
        off += (bytes + 255) & ~(size_t)255;
        return p;
    };
    u16*   XB     = (u16*)alloc((size_t)NN * 128 * 2);   // conv1 agg output / conv2 input
    u16*   X2B    = (u16*)alloc((size_t)NN * 128 * 2);   // conv2 output (pre-gate)
    u16*   YB     = (u16*)alloc((size_t)NN * 256 * 2);   // gemm output (rel|root)
    u16*   WT     = (u16*)alloc(3 * 256 * 128 * 2);      // 3 weight sets
    float* SRELP  = (float*)alloc((size_t)4 * NN * 4);   // per-chunk score partials
    float* SROOTP = (float*)alloc((size_t)4 * NN * 4);
    float* GATE   = (float*)alloc(NN * 4);
    float* KEEP   = (float*)alloc(NN * 4);
    float* CNT    = (float*)alloc(NN * 4);               // conv3 neighbor keep-count
    int*   DEG    = (int*)alloc(NN * 4);
    int*   NOFF   = (int*)alloc(NN * 4);
    int*   NORD   = (int*)alloc(NN * 4);                 // degree-sorted node order
    int*   CSR    = (int*)alloc((size_t)EE * 4);
    float* XS     = (float*)alloc((size_t)BG * 384 * 4); // pool outputs (exclusive stores)
    (void)ws_size; (void)n_in; (void)in_sizes; (void)out_size;

    // CSR build + degree-sort order (single kernel, per-graph LDS)
    csr_build_kernel<<<BG, 1024, 0, stream>>>(src, dst, NOFF, DEG, CSR, NORD);

    // prep all 3 weight sets
    prep_w_kernel<<<dim3(128, 3), 256, 0, stream>>>(W1_rel, W1_root, W2_rel, W2_root,
                                                    W3_rel, W3_root, WT);

    // ---- conv1 (fp32 input cast fused into gemm) ----
    gemm_kernel<1><<<dim3(NN / 128, 2), 256, 0, stream>>>(nullptr, x, nullptr, WT, YB);
    agg_kernel<0><<<BG * 4, 1024, 0, stream>>>(YB, CSR, NOFF, DEG, NORD, b1,
                                               nullptr, nullptr, XB,
                                               nullptr, nullptr, nullptr, nullptr,
                                               XS, 0, 1.f / 1024.f);

    // ---- conv2 (+ fused score partial dots) ----
    gemm_kernel<0><<<dim3(NN / 128, 2), 256, 0, stream>>>(XB, nullptr, nullptr, WT + 32768, YB);
    agg_kernel<1><<<BG * 4, 1024, 0, stream>>>(YB, CSR, NOFF, DEG, NORD, b2,
                                               nullptr, nullptr, X2B,
                                               Ws_rel, Ws_root, SRELP, SROOTP,
                                               XS, 128, 1.f / 1024.f);

    // ---- SAGPooling (score sum + topk + keep-count) ----
    topk_kernel<<<BG, 1024, 0, stream>>>(SRELP, SROOTP, bs, CSR, NOFF, DEG, KEEP, GATE, CNT);

    // ---- conv3 (gate fused into gemm A-staging) ----
    gemm_kernel<2><<<dim3(NN / 128, 2), 256, 0, stream>>>(X2B, nullptr, GATE, WT + 65536, YB);
    agg_kernel<2><<<BG * 4, 1024, 0, stream>>>(YB, CSR, NOFF, DEG, NORD, b3,
                                               KEEP, CNT, nullptr,
                                               nullptr, nullptr, nullptr, nullptr,
                                               XS, 256, 1.f / (float)KKEEP);

    // ---- MLP head ----
    mlp_kernel<<<BG, 512, 0, stream>>>(XS, Wl1, bl1, Wl2, bl2, (float*)d_out);
}

// Round 10
// 213.988 us; speedup vs baseline: 1.1422x; 1.1422x over previous
//
#include <hip/hip_runtime.h>
#include <hip/hip_bf16.h>

#define NN 65536
#define EE 1048576
#define BG 64
#define NPGC 1024
#define KKEEP 820

typedef unsigned short u16;
typedef unsigned int u32;
typedef __attribute__((ext_vector_type(4))) float f32x4;
typedef __attribute__((ext_vector_type(8))) short bf16x8;

__device__ __forceinline__ float bfu_lo(u32 u) {  // low bf16 -> f32
    u32 x = u << 16;
    return __builtin_bit_cast(float, x);
}
__device__ __forceinline__ float bfu_hi(u32 u) {  // high bf16 -> f32
    u32 x = u & 0xffff0000u;
    return __builtin_bit_cast(float, x);
}
__device__ __forceinline__ u16 fbf(float f) {
    __hip_bfloat16 h = __float2bfloat16(f);
    return __builtin_bit_cast(u16, h);
}
__device__ __forceinline__ u32 pack2(float a, float b) {
    return (u32)fbf(a) | ((u32)fbf(b) << 16);
}

// ---------------- CSR build + stable degree-sort order ----------------
// one block per graph: LDS histogram -> scan -> cursor fill -> bitonic sort of
// packed keys (deg<<10 | id), ascending => stable (deg asc, id asc) order.
__global__ __launch_bounds__(1024) void csr_build_kernel(const int* __restrict__ src,
                                                         const int* __restrict__ dst,
                                                         int* __restrict__ noff,
                                                         int* __restrict__ deg,
                                                         int* __restrict__ csr,
                                                         int* __restrict__ nord) {
    __shared__ int hist[NPGC];
    __shared__ int scan[NPGC];
    int g = blockIdx.x, t = threadIdx.x;
    hist[t] = 0;
    __syncthreads();
    int ebase = g * 16384;
    for (int i = t; i < 16384; i += 1024) atomicAdd(&hist[dst[ebase + i] & 1023], 1);
    __syncthreads();
    int d = hist[t];
    scan[t] = d;
    __syncthreads();
    for (int s = 1; s < NPGC; s <<= 1) {
        int add = (t >= s) ? scan[t - s] : 0;
        __syncthreads();
        scan[t] += add;
        __syncthreads();
    }
    int excl = scan[t] - d;
    int node = g * NPGC + t;
    deg[node] = d;
    noff[node] = ebase + excl;
    hist[t] = excl;  // fill cursor
    __syncthreads();
    for (int i = t; i < 16384; i += 1024) {
        int dl = dst[ebase + i] & 1023;
        int p = atomicAdd(&hist[dl], 1);
        csr[ebase + p] = src[ebase + i];
    }
    // stable (deg,id) order via bitonic sort of unique packed keys (scan is free now)
    __syncthreads();
    scan[t] = (d << 10) | t;
    __syncthreads();
    for (int k = 2; k <= NPGC; k <<= 1) {
        for (int j = k >> 1; j > 0; j >>= 1) {
            int ixj = t ^ j;
            if (ixj > t) {
                int a = scan[t], b = scan[ixj];
                bool up = ((t & k) == 0);
                if ((a > b) == up) { scan[t] = b; scan[ixj] = a; }
            }
            __syncthreads();
        }
    }
    nord[g * NPGC + t] = scan[t] & 1023;
}

// WT[l][col][k]: 3 weight sets at once. l = blockIdx.y.
__global__ void prep_w_kernel(const float* __restrict__ Wr1, const float* __restrict__ Wo1,
                              const float* __restrict__ Wr2, const float* __restrict__ Wo2,
                              const float* __restrict__ Wr3, const float* __restrict__ Wo3,
                              u16* __restrict__ WT) {
    int l = blockIdx.y;
    const float* Wrel = l == 0 ? Wr1 : (l == 1 ? Wr2 : Wr3);
    const float* Wroot = l == 0 ? Wo1 : (l == 1 ? Wo2 : Wo3);
    int idx = blockIdx.x * 256 + threadIdx.x;  // 32768
    int col = idx >> 7, k = idx & 127;
    float v = (col < 128) ? Wrel[k * 128 + col] : Wroot[k * 128 + (col - 128)];
    WT[l * 32768 + idx] = fbf(v);
}

// ---------------- GEMM: Y[N][256] = A[N][128] @ Wcat[128][256]  (bf16 MFMA, fp32 acc)
// MODE 0: A = bf16 Xb.  MODE 1: A = fp32 Xf (cast fused, conv1).
// MODE 2: A = bf16 Xb * gate[row] (gate fused, conv3).
template <int MODE>
__global__ __launch_bounds__(256, 2) void gemm_kernel(const u16* __restrict__ Xb,
                                                      const float* __restrict__ Xf,
                                                      const float* __restrict__ gate,
                                                      const u16* __restrict__ WT,
                                                      u16* __restrict__ Y) {
    __shared__ u16 As[128][72];
    __shared__ u16 Bs[128][72];
    int rb = blockIdx.x * 128;
    int cb = blockIdx.y * 128;
    int tid = threadIdx.x;
    int lane = tid & 63, wid = tid >> 6;
    int wr = (wid >> 1) << 6, wc = (wid & 1) << 6;
    int lr = lane & 15, lk = (lane >> 4) << 3;
    f32x4 acc[4][4] = {};

    for (int half = 0; half < 2; ++half) {
        int k0 = half << 6;
        if (half) __syncthreads();
        for (int i = tid; i < 1024; i += 256) {
            int r = i >> 3, c = (i & 7) << 3;
            uint4 av;
            if (MODE == 0) {
                av = *reinterpret_cast<const uint4*>(Xb + (size_t)(rb + r) * 128 + k0 + c);
            } else if (MODE == 1) {
                float4 f0 = *reinterpret_cast<const float4*>(Xf + (size_t)(rb + r) * 128 + k0 + c);
                float4 f1 = *reinterpret_cast<const float4*>(Xf + (size_t)(rb + r) * 128 + k0 + c + 4);
                av.x = pack2(f0.x, f0.y);
                av.y = pack2(f0.z, f0.w);
                av.z = pack2(f1.x, f1.y);
                av.w = pack2(f1.z, f1.w);
            } else {
                float g = gate[rb + r];
                uint4 w = *reinterpret_cast<const uint4*>(Xb + (size_t)(rb + r) * 128 + k0 + c);
                av.x = pack2(bfu_lo(w.x) * g, bfu_hi(w.x) * g);
                av.y = pack2(bfu_lo(w.y) * g, bfu_hi(w.y) * g);
                av.z = pack2(bfu_lo(w.z) * g, bfu_hi(w.z) * g);
                av.w = pack2(bfu_lo(w.w) * g, bfu_hi(w.w) * g);
            }
            *reinterpret_cast<uint4*>(&As[r][c]) = av;
            *reinterpret_cast<uint4*>(&Bs[r][c]) =
                *reinterpret_cast<const uint4*>(WT + (cb + r) * 128 + k0 + c);
        }
        __syncthreads();
        for (int kk = 0; kk < 64; kk += 32) {
            bf16x8 a[4], b[4];
            for (int m = 0; m < 4; ++m)
                a[m] = *reinterpret_cast<const bf16x8*>(&As[wr + m * 16 + lr][kk + lk]);
            for (int n = 0; n < 4; ++n)
                b[n] = *reinterpret_cast<const bf16x8*>(&Bs[wc + n * 16 + lr][kk + lk]);
            for (int m = 0; m < 4; ++m)
                for (int n = 0; n < 4; ++n)
                    acc[m][n] = __builtin_amdgcn_mfma_f32_16x16x32_bf16(a[m], b[n], acc[m][n], 0, 0, 0);
        }
    }
    int orow0 = rb + wr + ((lane >> 4) << 2);
    int ocol0 = cb + wc + (lane & 15);
    for (int m = 0; m < 4; ++m)
        for (int n = 0; n < 4; ++n)
            for (int r = 0; r < 4; ++r)
                Y[(size_t)(orow0 + m * 16 + r) * 256 + ocol0 + n * 16] = fbf(acc[m][n][r]);
}

// ---------------- LDS-staged aggregate + combine + relu + pool (+score) ----------------
// Block = (graph, 32-feature chunk). Stage all 1024 rel-rows' chunk into LDS
// feature-major (sst[fp][node], u32 = 2 bf16). Thread t owns node nord[t]
// (degree-sorted => wave-uniform edge loops) and accumulates via LDS reads.
// Pool per (graph,chunk) is exclusive -> plain stores, no atomics.
// LAYER 0: conv1 (outb). LAYER 1: conv2 (outb + score partials). LAYER 2: conv3 (keep/cnt).
template <int LAYER>
__global__ __launch_bounds__(1024, 4) void agg_kernel(const u16* __restrict__ Y,
                                                      const int* __restrict__ csr,
                                                      const int* __restrict__ noff,
                                                      const int* __restrict__ deg,
                                                      const int* __restrict__ nord,
                                                      const float* __restrict__ bias,
                                                      const float* __restrict__ keep,
                                                      const float* __restrict__ cntg,
                                                      u16* __restrict__ outb,
                                                      const float* __restrict__ wsrel,
                                                      const float* __restrict__ wsroot,
                                                      float* __restrict__ srelp,
                                                      float* __restrict__ srootp,
                                                      float* __restrict__ xs,
                                                      int base, float invdenom) {
    __shared__ u32 sst[16 * 1024];
    __shared__ float pool2[32 * 33];
    int g = blockIdx.x >> 2, c = blockIdx.x & 3;
    int t = threadIdx.x;
    int nbase = g * NPGC;

    // stage: thread t loads node t's 64B chunk (one cache line) -> 16 b32 LDS writes
    {
        const uint4* sp = reinterpret_cast<const uint4*>(Y + (size_t)(nbase + t) * 256 + c * 32);
        uint4 q0 = sp[0], q1 = sp[1], q2 = sp[2], q3 = sp[3];
        sst[0 * 1024 + t] = q0.x;  sst[1 * 1024 + t] = q0.y;
        sst[2 * 1024 + t] = q0.z;  sst[3 * 1024 + t] = q0.w;
        sst[4 * 1024 + t] = q1.x;  sst[5 * 1024 + t] = q1.y;
        sst[6 * 1024 + t] = q1.z;  sst[7 * 1024 + t] = q1.w;
        sst[8 * 1024 + t] = q2.x;  sst[9 * 1024 + t] = q2.y;
        sst[10 * 1024 + t] = q2.z; sst[11 * 1024 + t] = q2.w;
        sst[12 * 1024 + t] = q3.x; sst[13 * 1024 + t] = q3.y;
        sst[14 * 1024 + t] = q3.z; sst[15 * 1024 + t] = q3.w;
    }

    int nloc = nord[nbase + t];
    int node = nbase + nloc;
    int off = noff[node], dg = deg[node];
    float ki = 1.f, cnt;
    if (LAYER == 2) {
        ki = keep[node];
        cnt = cntg[node];
    } else {
        cnt = (float)dg;
    }
    __syncthreads();

    float accL[16] = {0.f, 0.f, 0.f, 0.f, 0.f, 0.f, 0.f, 0.f,
                      0.f, 0.f, 0.f, 0.f, 0.f, 0.f, 0.f, 0.f};
    float accH[16] = {0.f, 0.f, 0.f, 0.f, 0.f, 0.f, 0.f, 0.f,
                      0.f, 0.f, 0.f, 0.f, 0.f, 0.f, 0.f, 0.f};
    if (LAYER != 2 || ki != 0.f) {
        int nbr = (dg > 0) ? (csr[off] & 1023) : 0;
        for (int e = 0; e < dg; ++e) {
            int nxt = (e + 1 < dg) ? (csr[off + e + 1] & 1023) : 0;
#pragma unroll
            for (int fp = 0; fp < 16; ++fp) {
                u32 v = sst[fp * 1024 + nbr];
                accL[fp] += bfu_lo(v);
                accH[fp] += bfu_hi(v);
            }
            nbr = nxt;
        }
    }

    float inv = ki / fmaxf(cnt, 1.f);
    const uint4* rp = reinterpret_cast<const uint4*>(Y + (size_t)node * 256 + 128 + c * 32);
    uint4 r0 = rp[0], r1 = rp[1], r2 = rp[2], r3 = rp[3];
    u32 rr[16] = {r0.x, r0.y, r0.z, r0.w, r1.x, r1.y, r1.z, r1.w,
                  r2.x, r2.y, r2.z, r2.w, r3.x, r3.y, r3.z, r3.w};
    u32 pk[16];
    float pr = 0.f, po = 0.f;
#pragma unroll
    for (int fp = 0; fp < 16; ++fp) {
        float lo = fmaxf(accL[fp] * inv + bias[c * 32 + 2 * fp] + bfu_lo(rr[fp]), 0.f) * ki;
        float hi = fmaxf(accH[fp] * inv + bias[c * 32 + 2 * fp + 1] + bfu_hi(rr[fp]), 0.f) * ki;
        if (LAYER == 1) {
            pr += lo * wsrel[c * 32 + 2 * fp] + hi * wsrel[c * 32 + 2 * fp + 1];
            po += lo * wsroot[c * 32 + 2 * fp] + hi * wsroot[c * 32 + 2 * fp + 1];
        }
        pk[fp] = pack2(lo, hi);
    }
    if (LAYER != 2) {
        uint4* op = reinterpret_cast<uint4*>(outb + (size_t)node * 128 + c * 32);
        uint4 o0 = {pk[0], pk[1], pk[2], pk[3]};
        uint4 o1 = {pk[4], pk[5], pk[6], pk[7]};
        uint4 o2 = {pk[8], pk[9], pk[10], pk[11]};
        uint4 o3 = {pk[12], pk[13], pk[14], pk[15]};
        op[0] = o0; op[1] = o1; op[2] = o2; op[3] = o3;
    }
    if (LAYER == 1) {
        srelp[(size_t)c * NN + node] = pr;
        srootp[(size_t)c * NN + node] = po;
    }

    __syncthreads();  // all LDS gathers done; reuse sst for pool values
#pragma unroll
    for (int fp = 0; fp < 16; ++fp) sst[fp * 1024 + t] = pk[fp];
    __syncthreads();

    // pool reduce: f = feature in chunk, sub = node class mod 32
    {
        int f = t >> 5, sub = t & 31;
        float s = 0.f;
#pragma unroll 4
        for (int k = 0; k < 32; ++k) {
            u32 v = sst[(f >> 1) * 1024 + sub + 32 * k];
            s += (f & 1) ? bfu_hi(v) : bfu_lo(v);
        }
        pool2[f * 33 + sub] = s;
    }
    __syncthreads();
    if (t < 32) {
        float s = 0.f;
#pragma unroll 4
        for (int sub = 0; sub < 32; ++sub) s += pool2[t * 33 + sub];
        xs[g * 384 + base + c * 32 + t] = s * invdenom;
    }
}

// ---------------- per-graph top-K (score sum + bitonic sort + keep-count) ----------------
__global__ __launch_bounds__(1024) void topk_kernel(const float* __restrict__ srelp,
                                                    const float* __restrict__ srootp,
                                                    const float* __restrict__ bs,
                                                    const int* __restrict__ csr,
                                                    const int* __restrict__ noff,
                                                    const int* __restrict__ deg,
                                                    float* __restrict__ keep,
                                                    float* __restrict__ gate,
                                                    float* __restrict__ cntg) {
    __shared__ float sc[NPGC];
    __shared__ int si[NPGC];
    __shared__ float ssr[NPGC];
    int g = blockIdx.x, t = threadIdx.x;
    int node = g * NPGC + t;
    // fixed-order sum of the 4 chunk partials (deterministic)
    ssr[t] = srelp[node] + srelp[NN + node] + srelp[2 * NN + node] + srelp[3 * NN + node];
    float sroot = srootp[node] + srootp[NN + node] + srootp[2 * NN + node] + srootp[3 * NN + node];
    __syncthreads();
    int off = noff[node], dg = deg[node];
    float s = 0.f;
    for (int e = 0; e < dg; ++e) s += ssr[csr[off + e] & 1023];
    sc[t] = s / fmaxf((float)dg, 1.0f) + bs[0] + sroot;
    si[t] = t;
    __syncthreads();
    for (int k = 2; k <= NPGC; k <<= 1) {
        for (int j = k >> 1; j > 0; j >>= 1) {
            int ixj = t ^ j;
            if (ixj > t) {
                float a = sc[t], b = sc[ixj];
                int ai = si[t], bi = si[ixj];
                bool less = (a > b) || (a == b && ai < bi);  // desc, idx-asc tiebreak
                bool up = ((t & k) == 0);
                if (less != up) { sc[t] = b; sc[ixj] = a; si[t] = bi; si[ixj] = ai; }
            }
            __syncthreads();
        }
    }
    int oloc = si[t];
    float kf = (t < KKEEP) ? 1.f : 0.f;
    keep[g * NPGC + oloc] = kf;
    gate[g * NPGC + oloc] = kf * tanhf(sc[t]);
    ssr[oloc] = kf;  // reuse as keep flags
    __syncthreads();
    // conv3 neighbor keep-count
    float cnt = 0.f;
    for (int e = 0; e < dg; ++e) cnt += ssr[csr[off + e] & 1023];
    cntg[node] = cnt;
}

// ---------------- MLP head + log_softmax; one block of 512 per graph.
__global__ __launch_bounds__(512) void mlp_kernel(const float* __restrict__ xs,
                                                  const float* __restrict__ Wl1,
                                                  const float* __restrict__ bl1,
                                                  const float* __restrict__ Wl2,
                                                  const float* __restrict__ bl2,
                                                  float* __restrict__ out) {
    __shared__ float xsl[384];
    __shared__ float part[4][128];
    __shared__ float wl2s[1280];
    __shared__ float wred[2][10];
    __shared__ float lgs[10];
    int g = blockIdx.x, tid = threadIdx.x;
    int t = tid & 127, kg = tid >> 7;

    for (int i = tid; i < 1280; i += 512) wl2s[i] = Wl2[i];
    if (tid < 384) xsl[tid] = xs[g * 384 + tid];
    __syncthreads();

    float p = 0.f;
    int k0 = kg * 96;
#pragma unroll 8
    for (int k = 0; k < 96; ++k) p += xsl[k0 + k] * Wl1[(k0 + k) * 128 + t];
    part[kg][t] = p;
    __syncthreads();

    if (tid < 128) {
        float h = fmaxf(bl1[t] + part[0][t] + part[1][t] + part[2][t] + part[3][t], 0.f);
        float pc[10];
#pragma unroll
        for (int c = 0; c < 10; ++c) pc[c] = h * wl2s[t * 10 + c];
#pragma unroll
        for (int d = 1; d < 64; d <<= 1) {
#pragma unroll
            for (int c = 0; c < 10; ++c) pc[c] += __shfl_xor(pc[c], d, 64);
        }
        if ((t & 63) == 0) {
#pragma unroll
            for (int c = 0; c < 10; ++c) wred[t >> 6][c] = pc[c];
        }
    }
    __syncthreads();
    if (tid < 10) lgs[tid] = wred[0][tid] + wred[1][tid] + bl2[tid];
    __syncthreads();
    if (tid < 10) {
        float m = lgs[0];
#pragma unroll
        for (int c = 1; c < 10; ++c) m = fmaxf(m, lgs[c]);
        float s = 0.f;
#pragma unroll
        for (int c = 0; c < 10; ++c) s += expf(lgs[c] - m);
        out[g * 10 + tid] = lgs[tid] - m - logf(s);
    }
}

extern "C" void kernel_launch(void* const* d_in, const int* in_sizes, int n_in,
                              void* d_out, int out_size, void* d_ws, size_t ws_size,
                              hipStream_t stream) {
    const float* x       = (const float*)d_in[0];
    const int*   src     = (const int*)d_in[1];
    const int*   dst     = (const int*)d_in[2];
    const float* W1_rel  = (const float*)d_in[3];
    const float* b1      = (const float*)d_in[4];
    const float* W1_root = (const float*)d_in[5];
    const float* W2_rel  = (const float*)d_in[6];
    const float* b2      = (const float*)d_in[7];
    const float* W2_root = (const float*)d_in[8];
    const float* W3_rel  = (const float*)d_in[9];
    const float* b3      = (const float*)d_in[10];
    const float* W3_root = (const float*)d_in[11];
    const float* Ws_rel  = (const float*)d_in[12];
    const float* bs      = (const float*)d_in[13];
    const float* Ws_root = (const float*)d_in[14];
    const float* Wl1     = (const float*)d_in[15];
    const float* bl1     = (const float*)d_in[16];
    const float* Wl2     = (const float*)d_in[17];
    const float* bl2     = (const float*)d_in[18];

    char* ws = (char*)d_ws;
    size_t off = 0;
    auto alloc = [&](size_t bytes) -> void* {
        void* p = ws + off;
        off += (bytes + 255) & ~(size_t)255;
        return p;
    };
    u16*   XB     = (u16*)alloc((size_t)NN * 128 * 2);   // conv1 agg output / conv2 input
    u16*   X2B    = (u16*)alloc((size_t)NN * 128 * 2);   // conv2 output (pre-gate)
    u16*   YB     = (u16*)alloc((size_t)NN * 256 * 2);   // gemm output (rel|root)
    u16*   WT     = (u16*)alloc(3 * 256 * 128 * 2);      // 3 weight sets
    float* SRELP  = (float*)alloc((size_t)4 * NN * 4);   // per-chunk score partials
    float* SROOTP = (float*)alloc((size_t)4 * NN * 4);
    float* GATE   = (float*)alloc(NN * 4);
    float* KEEP   = (float*)alloc(NN * 4);
    float* CNT    = (float*)alloc(NN * 4);               // conv3 neighbor keep-count
    int*   DEG    = (int*)alloc(NN * 4);
    int*   NOFF   = (int*)alloc(NN * 4);
    int*   NORD   = (int*)alloc(NN * 4);                 // degree-sorted node order
    int*   CSR    = (int*)alloc((size_t)EE * 4);
    float* XS     = (float*)alloc((size_t)BG * 384 * 4); // pool outputs (exclusive stores)
    (void)ws_size; (void)n_in; (void)in_sizes; (void)out_size;

    // CSR build + degree-sort order (single kernel, per-graph LDS)
    csr_build_kernel<<<BG, 1024, 0, stream>>>(src, dst, NOFF, DEG, CSR, NORD);

    // prep all 3 weight sets
    prep_w_kernel<<<dim3(128, 3), 256, 0, stream>>>(W1_rel, W1_root, W2_rel, W2_root,
                                                    W3_rel, W3_root, WT);

    // ---- conv1 (fp32 input cast fused into gemm) ----
    gemm_kernel<1><<<dim3(NN / 128, 2), 256, 0, stream>>>(nullptr, x, nullptr, WT, YB);
    agg_kernel<0><<<BG * 4, 1024, 0, stream>>>(YB, CSR, NOFF, DEG, NORD, b1,
                                               nullptr, nullptr, XB,
                                               nullptr, nullptr, nullptr, nullptr,
                                               XS, 0, 1.f / 1024.f);

    // ---- conv2 (+ fused score partial dots) ----
    gemm_kernel<0><<<dim3(NN / 128, 2), 256, 0, stream>>>(XB, nullptr, nullptr, WT + 32768, YB);
    agg_kernel<1><<<BG * 4, 1024, 0, stream>>>(YB, CSR, NOFF, DEG, NORD, b2,
                                               nullptr, nullptr, X2B,
                                               Ws_rel, Ws_root, SRELP, SROOTP,
                                               XS, 128, 1.f / 1024.f);

    // ---- SAGPooling (score sum + topk + keep-count) ----
    topk_kernel<<<BG, 1024, 0, stream>>>(SRELP, SROOTP, bs, CSR, NOFF, DEG, KEEP, GATE, CNT);

    // ---- conv3 (gate fused into gemm A-staging) ----
    gemm_kernel<2><<<dim3(NN / 128, 2), 256, 0, stream>>>(X2B, nullptr, GATE, WT + 65536, YB);
    agg_kernel<2><<<BG * 4, 1024, 0, stream>>>(YB, CSR, NOFF, DEG, NORD, b3,
                                               KEEP, CNT, nullptr,
                                               nullptr, nullptr, nullptr, nullptr,
                                               XS, 256, 1.f / (float)KKEEP);

    // ---- MLP head ----
    mlp_kernel<<<BG, 512, 0, stream>>>(XS, Wl1, bl1, Wl2, bl2, (float*)d_out);
}

// Round 11
// 203.844 us; speedup vs baseline: 1.1990x; 1.0498x over previous
//
#include <hip/hip_runtime.h>
#include <hip/hip_bf16.h>

#define NN 65536
#define EE 1048576
#define BG 64
#define NPGC 1024
#define KKEEP 820

typedef unsigned short u16;
typedef unsigned int u32;
typedef __attribute__((ext_vector_type(4))) float f32x4;
typedef __attribute__((ext_vector_type(8))) short bf16x8;

__device__ __forceinline__ float bfu_lo(u32 u) {  // low bf16 -> f32
    u32 x = u << 16;
    return __builtin_bit_cast(float, x);
}
__device__ __forceinline__ float bfu_hi(u32 u) {  // high bf16 -> f32
    u32 x = u & 0xffff0000u;
    return __builtin_bit_cast(float, x);
}
__device__ __forceinline__ u16 fbf(float f) {
    __hip_bfloat16 h = __float2bfloat16(f);
    return __builtin_bit_cast(u16, h);
}
__device__ __forceinline__ u32 pack2(float a, float b) {
    return (u32)fbf(a) | ((u32)fbf(b) << 16);
}

// ---------------- CSR build + stable degree-sort order ----------------
// one block per graph. Latency-optimized: all 32 edge loads issued up front
// (registers), shuffle-based scan (2 syncs), hybrid bitonic (shuffle phases
// j<64, LDS only for 10 cross-wave phases).
__global__ __launch_bounds__(1024) void csr_build_kernel(const int* __restrict__ src,
                                                         const int* __restrict__ dst,
                                                         int* __restrict__ noff,
                                                         int* __restrict__ deg,
                                                         int* __restrict__ csr,
                                                         int* __restrict__ nord) {
    __shared__ int hist[NPGC];
    __shared__ int xch[NPGC];
    __shared__ int wsum[16];
    int g = blockIdx.x, t = threadIdx.x;
    int lane = t & 63, wid = t >> 6;
    int ebase = g * 16384;

    // issue all edge loads up front (32 in flight)
    int dv[16], sv[16];
#pragma unroll
    for (int j = 0; j < 16; ++j) dv[j] = dst[ebase + (j << 10) + t] & 1023;
#pragma unroll
    for (int j = 0; j < 16; ++j) sv[j] = src[ebase + (j << 10) + t];

    hist[t] = 0;
    __syncthreads();
#pragma unroll
    for (int j = 0; j < 16; ++j) atomicAdd(&hist[dv[j]], 1);
    __syncthreads();

    int d = hist[t];

    // exclusive scan via wave shfl + cross-wave combine
    int v = d;
#pragma unroll
    for (int s = 1; s < 64; s <<= 1) {
        int u = __shfl_up(v, s, 64);
        if (lane >= s) v += u;
    }
    if (lane == 63) wsum[wid] = v;
    __syncthreads();
    if (t < 16) {
        int w = wsum[t];
#pragma unroll
        for (int s = 1; s < 16; s <<= 1) {
            int u = __shfl_up(w, s, 64);
            if (t >= s) w += u;
        }
        wsum[t] = w;
    }
    __syncthreads();
    int excl = ((wid > 0) ? wsum[wid - 1] : 0) + v - d;

    int node = g * NPGC + t;
    deg[node] = d;
    noff[node] = ebase + excl;
    hist[t] = excl;  // fill cursor
    __syncthreads();

    // fill: 16 independent atomic_rtn -> store chains (pipelined)
#pragma unroll
    for (int j = 0; j < 16; ++j) {
        int p = atomicAdd(&hist[dv[j]], 1);
        csr[ebase + p] = sv[j];
    }

    // stable (deg,id) asc order via hybrid bitonic on unique keys
    int key = (d << 10) | t;
    for (int k = 2; k <= NPGC; k <<= 1) {
        for (int j = k >> 1; j > 0; j >>= 1) {
            int partner;
            if (j >= 64) {
                xch[t] = key;
                __syncthreads();
                partner = xch[t ^ j];
                __syncthreads();
            } else {
                partner = __shfl_xor(key, j, 64);
            }
            bool up = ((t & k) == 0);
            bool lower = ((t & j) == 0);
            int mn = key < partner ? key : partner;
            int mx = key < partner ? partner : key;
            key = (up == lower) ? mn : mx;
        }
    }
    nord[g * NPGC + t] = key & 1023;
}

// WT[l][col][k]: 3 weight sets at once. l = blockIdx.y.
__global__ void prep_w_kernel(const float* __restrict__ Wr1, const float* __restrict__ Wo1,
                              const float* __restrict__ Wr2, const float* __restrict__ Wo2,
                              const float* __restrict__ Wr3, const float* __restrict__ Wo3,
                              u16* __restrict__ WT) {
    int l = blockIdx.y;
    const float* Wrel = l == 0 ? Wr1 : (l == 1 ? Wr2 : Wr3);
    const float* Wroot = l == 0 ? Wo1 : (l == 1 ? Wo2 : Wo3);
    int idx = blockIdx.x * 256 + threadIdx.x;  // 32768
    int col = idx >> 7, k = idx & 127;
    float v = (col < 128) ? Wrel[k * 128 + col] : Wroot[k * 128 + (col - 128)];
    WT[l * 32768 + idx] = fbf(v);
}

// ---------------- GEMM: Y[N][256] = A[N][128] @ Wcat[128][256]  (bf16 MFMA, fp32 acc)
// MODE 0: A = bf16 Xb.  MODE 1: A = fp32 Xf (cast fused, conv1).
// MODE 2: A = bf16 Xb * gate[row] (gate fused, conv3).
template <int MODE>
__global__ __launch_bounds__(256, 2) void gemm_kernel(const u16* __restrict__ Xb,
                                                      const float* __restrict__ Xf,
                                                      const float* __restrict__ gate,
                                                      const u16* __restrict__ WT,
                                                      u16* __restrict__ Y) {
    __shared__ u16 As[128][72];
    __shared__ u16 Bs[128][72];
    int rb = blockIdx.x * 128;
    int cb = blockIdx.y * 128;
    int tid = threadIdx.x;
    int lane = tid & 63, wid = tid >> 6;
    int wr = (wid >> 1) << 6, wc = (wid & 1) << 6;
    int lr = lane & 15, lk = (lane >> 4) << 3;
    f32x4 acc[4][4] = {};

    for (int half = 0; half < 2; ++half) {
        int k0 = half << 6;
        if (half) __syncthreads();
        for (int i = tid; i < 1024; i += 256) {
            int r = i >> 3, c = (i & 7) << 3;
            uint4 av;
            if (MODE == 0) {
                av = *reinterpret_cast<const uint4*>(Xb + (size_t)(rb + r) * 128 + k0 + c);
            } else if (MODE == 1) {
                float4 f0 = *reinterpret_cast<const float4*>(Xf + (size_t)(rb + r) * 128 + k0 + c);
                float4 f1 = *reinterpret_cast<const float4*>(Xf + (size_t)(rb + r) * 128 + k0 + c + 4);
                av.x = pack2(f0.x, f0.y);
                av.y = pack2(f0.z, f0.w);
                av.z = pack2(f1.x, f1.y);
                av.w = pack2(f1.z, f1.w);
            } else {
                float g = gate[rb + r];
                uint4 w = *reinterpret_cast<const uint4*>(Xb + (size_t)(rb + r) * 128 + k0 + c);
                av.x = pack2(bfu_lo(w.x) * g, bfu_hi(w.x) * g);
                av.y = pack2(bfu_lo(w.y) * g, bfu_hi(w.y) * g);
                av.z = pack2(bfu_lo(w.z) * g, bfu_hi(w.z) * g);
                av.w = pack2(bfu_lo(w.w) * g, bfu_hi(w.w) * g);
            }
            *reinterpret_cast<uint4*>(&As[r][c]) = av;
            *reinterpret_cast<uint4*>(&Bs[r][c]) =
                *reinterpret_cast<const uint4*>(WT + (cb + r) * 128 + k0 + c);
        }
        __syncthreads();
        for (int kk = 0; kk < 64; kk += 32) {
            bf16x8 a[4], b[4];
            for (int m = 0; m < 4; ++m)
                a[m] = *reinterpret_cast<const bf16x8*>(&As[wr + m * 16 + lr][kk + lk]);
            for (int n = 0; n < 4; ++n)
                b[n] = *reinterpret_cast<const bf16x8*>(&Bs[wc + n * 16 + lr][kk + lk]);
            for (int m = 0; m < 4; ++m)
                for (int n = 0; n < 4; ++n)
                    acc[m][n] = __builtin_amdgcn_mfma_f32_16x16x32_bf16(a[m], b[n], acc[m][n], 0, 0, 0);
        }
    }
    int orow0 = rb + wr + ((lane >> 4) << 2);
    int ocol0 = cb + wc + (lane & 15);
    for (int m = 0; m < 4; ++m)
        for (int n = 0; n < 4; ++n)
            for (int r = 0; r < 4; ++r)
                Y[(size_t)(orow0 + m * 16 + r) * 256 + ocol0 + n * 16] = fbf(acc[m][n][r]);
}

// ---------------- LDS-staged aggregate + combine + relu + pool (+score) ----------------
// Block = (graph, 32-feature chunk). Stage all 1024 rel-rows' chunk into LDS
// feature-major (sst[fp][node], u32 = 2 bf16). Thread t owns node nord[t]
// (degree-sorted => wave-uniform edge loops) and accumulates via LDS reads.
// Pool per (graph,chunk) is exclusive -> plain stores, no atomics.
// LAYER 0: conv1 (outb). LAYER 1: conv2 (outb + score partials). LAYER 2: conv3 (keep/cnt).
template <int LAYER>
__global__ __launch_bounds__(1024, 4) void agg_kernel(const u16* __restrict__ Y,
                                                      const int* __restrict__ csr,
                                                      const int* __restrict__ noff,
                                                      const int* __restrict__ deg,
                                                      const int* __restrict__ nord,
                                                      const float* __restrict__ bias,
                                                      const float* __restrict__ keep,
                                                      const float* __restrict__ cntg,
                                                      u16* __restrict__ outb,
                                                      const float* __restrict__ wsrel,
                                                      const float* __restrict__ wsroot,
                                                      float* __restrict__ srelp,
                                                      float* __restrict__ srootp,
                                                      float* __restrict__ xs,
                                                      int base, float invdenom) {
    __shared__ u32 sst[16 * 1024];
    __shared__ float pool2[32 * 33];
    int g = blockIdx.x >> 2, c = blockIdx.x & 3;
    int t = threadIdx.x;
    int nbase = g * NPGC;

    // stage: thread t loads node t's 64B chunk (one cache line) -> 16 b32 LDS writes
    {
        const uint4* sp = reinterpret_cast<const uint4*>(Y + (size_t)(nbase + t) * 256 + c * 32);
        uint4 q0 = sp[0], q1 = sp[1], q2 = sp[2], q3 = sp[3];
        sst[0 * 1024 + t] = q0.x;  sst[1 * 1024 + t] = q0.y;
        sst[2 * 1024 + t] = q0.z;  sst[3 * 1024 + t] = q0.w;
        sst[4 * 1024 + t] = q1.x;  sst[5 * 1024 + t] = q1.y;
        sst[6 * 1024 + t] = q1.z;  sst[7 * 1024 + t] = q1.w;
        sst[8 * 1024 + t] = q2.x;  sst[9 * 1024 + t] = q2.y;
        sst[10 * 1024 + t] = q2.z; sst[11 * 1024 + t] = q2.w;
        sst[12 * 1024 + t] = q3.x; sst[13 * 1024 + t] = q3.y;
        sst[14 * 1024 + t] = q3.z; sst[15 * 1024 + t] = q3.w;
    }

    int nloc = nord[nbase + t];
    int node = nbase + nloc;
    int off = noff[node], dg = deg[node];
    float ki = 1.f, cnt;
    if (LAYER == 2) {
        ki = keep[node];
        cnt = cntg[node];
    } else {
        cnt = (float)dg;
    }
    __syncthreads();

    float accL[16] = {0.f, 0.f, 0.f, 0.f, 0.f, 0.f, 0.f, 0.f,
                      0.f, 0.f, 0.f, 0.f, 0.f, 0.f, 0.f, 0.f};
    float accH[16] = {0.f, 0.f, 0.f, 0.f, 0.f, 0.f, 0.f, 0.f,
                      0.f, 0.f, 0.f, 0.f, 0.f, 0.f, 0.f, 0.f};
    if (LAYER != 2 || ki != 0.f) {
        int nbr = (dg > 0) ? (csr[off] & 1023) : 0;
        for (int e = 0; e < dg; ++e) {
            int nxt = (e + 1 < dg) ? (csr[off + e + 1] & 1023) : 0;
#pragma unroll
            for (int fp = 0; fp < 16; ++fp) {
                u32 v = sst[fp * 1024 + nbr];
                accL[fp] += bfu_lo(v);
                accH[fp] += bfu_hi(v);
            }
            nbr = nxt;
        }
    }

    float inv = ki / fmaxf(cnt, 1.f);
    const uint4* rp = reinterpret_cast<const uint4*>(Y + (size_t)node * 256 + 128 + c * 32);
    uint4 r0 = rp[0], r1 = rp[1], r2 = rp[2], r3 = rp[3];
    u32 rr[16] = {r0.x, r0.y, r0.z, r0.w, r1.x, r1.y, r1.z, r1.w,
                  r2.x, r2.y, r2.z, r2.w, r3.x, r3.y, r3.z, r3.w};
    u32 pk[16];
    float pr = 0.f, po = 0.f;
#pragma unroll
    for (int fp = 0; fp < 16; ++fp) {
        float lo = fmaxf(accL[fp] * inv + bias[c * 32 + 2 * fp] + bfu_lo(rr[fp]), 0.f) * ki;
        float hi = fmaxf(accH[fp] * inv + bias[c * 32 + 2 * fp + 1] + bfu_hi(rr[fp]), 0.f) * ki;
        if (LAYER == 1) {
            pr += lo * wsrel[c * 32 + 2 * fp] + hi * wsrel[c * 32 + 2 * fp + 1];
            po += lo * wsroot[c * 32 + 2 * fp] + hi * wsroot[c * 32 + 2 * fp + 1];
        }
        pk[fp] = pack2(lo, hi);
    }
    if (LAYER != 2) {
        uint4* op = reinterpret_cast<uint4*>(outb + (size_t)node * 128 + c * 32);
        uint4 o0 = {pk[0], pk[1], pk[2], pk[3]};
        uint4 o1 = {pk[4], pk[5], pk[6], pk[7]};
        uint4 o2 = {pk[8], pk[9], pk[10], pk[11]};
        uint4 o3 = {pk[12], pk[13], pk[14], pk[15]};
        op[0] = o0; op[1] = o1; op[2] = o2; op[3] = o3;
    }
    if (LAYER == 1) {
        srelp[(size_t)c * NN + node] = pr;
        srootp[(size_t)c * NN + node] = po;
    }

    __syncthreads();  // all LDS gathers done; reuse sst for pool values
#pragma unroll
    for (int fp = 0; fp < 16; ++fp) sst[fp * 1024 + t] = pk[fp];
    __syncthreads();

    // pool reduce: f = feature in chunk, sub = node class mod 32
    {
        int f = t >> 5, sub = t & 31;
        float s = 0.f;
#pragma unroll 4
        for (int k = 0; k < 32; ++k) {
            u32 v = sst[(f >> 1) * 1024 + sub + 32 * k];
            s += (f & 1) ? bfu_hi(v) : bfu_lo(v);
        }
        pool2[f * 33 + sub] = s;
    }
    __syncthreads();
    if (t < 32) {
        float s = 0.f;
#pragma unroll 4
        for (int sub = 0; sub < 32; ++sub) s += pool2[t * 33 + sub];
        xs[g * 384 + base + c * 32 + t] = s * invdenom;
    }
}

// ---------------- per-graph top-K (score sum + bitonic sort + keep-count) ----------------
__global__ __launch_bounds__(1024) void topk_kernel(const float* __restrict__ srelp,
                                                    const float* __restrict__ srootp,
                                                    const float* __restrict__ bs,
                                                    const int* __restrict__ csr,
                                                    const int* __restrict__ noff,
                                                    const int* __restrict__ deg,
                                                    float* __restrict__ keep,
                                                    float* __restrict__ gate,
                                                    float* __restrict__ cntg) {
    __shared__ float sc[NPGC];
    __shared__ int si[NPGC];
    __shared__ float ssr[NPGC];
    int g = blockIdx.x, t = threadIdx.x;
    int node = g * NPGC + t;
    // fixed-order sum of the 4 chunk partials (deterministic)
    ssr[t] = srelp[node] + srelp[NN + node] + srelp[2 * NN + node] + srelp[3 * NN + node];
    float sroot = srootp[node] + srootp[NN + node] + srootp[2 * NN + node] + srootp[3 * NN + node];
    __syncthreads();
    int off = noff[node], dg = deg[node];
    float s = 0.f;
    for (int e = 0; e < dg; ++e) s += ssr[csr[off + e] & 1023];
    sc[t] = s / fmaxf((float)dg, 1.0f) + bs[0] + sroot;
    si[t] = t;
    __syncthreads();
    for (int k = 2; k <= NPGC; k <<= 1) {
        for (int j = k >> 1; j > 0; j >>= 1) {
            int ixj = t ^ j;
            if (ixj > t) {
                float a = sc[t], b = sc[ixj];
                int ai = si[t], bi = si[ixj];
                bool less = (a > b) || (a == b && ai < bi);  // desc, idx-asc tiebreak
                bool up = ((t & k) == 0);
                if (less != up) { sc[t] = b; sc[ixj] = a; si[t] = bi; si[ixj] = ai; }
            }
            __syncthreads();
        }
    }
    int oloc = si[t];
    float kf = (t < KKEEP) ? 1.f : 0.f;
    keep[g * NPGC + oloc] = kf;
    gate[g * NPGC + oloc] = kf * tanhf(sc[t]);
    ssr[oloc] = kf;  // reuse as keep flags
    __syncthreads();
    // conv3 neighbor keep-count
    float cnt = 0.f;
    for (int e = 0; e < dg; ++e) cnt += ssr[csr[off + e] & 1023];
    cntg[node] = cnt;
}

// ---------------- MLP head + log_softmax; one block of 512 per graph.
__global__ __launch_bounds__(512) void mlp_kernel(const float* __restrict__ xs,
                                                  const float* __restrict__ Wl1,
                                                  const float* __restrict__ bl1,
                                                  const float* __restrict__ Wl2,
                                                  const float* __restrict__ bl2,
                                                  float* __restrict__ out) {
    __shared__ float xsl[384];
    __shared__ float part[4][128];
    __shared__ float wl2s[1280];
    __shared__ float wred[2][10];
    __shared__ float lgs[10];
    int g = blockIdx.x, tid = threadIdx.x;
    int t = tid & 127, kg = tid >> 7;

    for (int i = tid; i < 1280; i += 512) wl2s[i] = Wl2[i];
    if (tid < 384) xsl[tid] = xs[g * 384 + tid];
    __syncthreads();

    float p = 0.f;
    int k0 = kg * 96;
#pragma unroll 8
    for (int k = 0; k < 96; ++k) p += xsl[k0 + k] * Wl1[(k0 + k) * 128 + t];
    part[kg][t] = p;
    __syncthreads();

    if (tid < 128) {
        float h = fmaxf(bl1[t] + part[0][t] + part[1][t] + part[2][t] + part[3][t], 0.f);
        float pc[10];
#pragma unroll
        for (int c = 0; c < 10; ++c) pc[c] = h * wl2s[t * 10 + c];
#pragma unroll
        for (int d = 1; d < 64; d <<= 1) {
#pragma unroll
            for (int c = 0; c < 10; ++c) pc[c] += __shfl_xor(pc[c], d, 64);
        }
        if ((t & 63) == 0) {
#pragma unroll
            for (int c = 0; c < 10; ++c) wred[t >> 6][c] = pc[c];
        }
    }
    __syncthreads();
    if (tid < 10) lgs[tid] = wred[0][tid] + wred[1][tid] + bl2[tid];
    __syncthreads();
    if (tid < 10) {
        float m = lgs[0];
#pragma unroll
        for (int c = 1; c < 10; ++c) m = fmaxf(m, lgs[c]);
        float s = 0.f;
#pragma unroll
        for (int c = 0; c < 10; ++c) s += expf(lgs[c] - m);
        out[g * 10 + tid] = lgs[tid] - m - logf(s);
    }
}

extern "C" void kernel_launch(void* const* d_in, const int* in_sizes, int n_in,
                              void* d_out, int out_size, void* d_ws, size_t ws_size,
                              hipStream_t stream) {
    const float* x       = (const float*)d_in[0];
    const int*   src     = (const int*)d_in[1];
    const int*   dst     = (const int*)d_in[2];
    const float* W1_rel  = (const float*)d_in[3];
    const float* b1      = (const float*)d_in[4];
    const float* W1_root = (const float*)d_in[5];
    const float* W2_rel  = (const float*)d_in[6];
    const float* b2      = (const float*)d_in[7];
    const float* W2_root = (const float*)d_in[8];
    const float* W3_rel  = (const float*)d_in[9];
    const float* b3      = (const float*)d_in[10];
    const float* W3_root = (const float*)d_in[11];
    const float* Ws_rel  = (const float*)d_in[12];
    const float* bs      = (const float*)d_in[13];
    const float* Ws_root = (const float*)d_in[14];
    const float* Wl1     = (const float*)d_in[15];
    const float* bl1     = (const float*)d_in[16];
    const float* Wl2     = (const float*)d_in[17];
    const float* bl2     = (const float*)d_in[18];

    char* ws = (char*)d_ws;
    size_t off = 0;
    auto alloc = [&](size_t bytes) -> void* {
        void* p = ws + off;
        off += (bytes + 255) & ~(size_t)255;
        return p;
    };
    u16*   XB     = (u16*)alloc((size_t)NN * 128 * 2);   // conv1 agg output / conv2 input
    u16*   X2B    = (u16*)alloc((size_t)NN * 128 * 2);   // conv2 output (pre-gate)
    u16*   YB     = (u16*)alloc((size_t)NN * 256 * 2);   // gemm output (rel|root)
    u16*   WT     = (u16*)alloc(3 * 256 * 128 * 2);      // 3 weight sets
    float* SRELP  = (float*)alloc((size_t)4 * NN * 4);   // per-chunk score partials
    float* SROOTP = (float*)alloc((size_t)4 * NN * 4);
    float* GATE   = (float*)alloc(NN * 4);
    float* KEEP   = (float*)alloc(NN * 4);
    float* CNT    = (float*)alloc(NN * 4);               // conv3 neighbor keep-count
    int*   DEG    = (int*)alloc(NN * 4);
    int*   NOFF   = (int*)alloc(NN * 4);
    int*   NORD   = (int*)alloc(NN * 4);                 // degree-sorted node order
    int*   CSR    = (int*)alloc((size_t)EE * 4);
    float* XS     = (float*)alloc((size_t)BG * 384 * 4); // pool outputs (exclusive stores)
    (void)ws_size; (void)n_in; (void)in_sizes; (void)out_size;

    // CSR build + degree-sort order (single kernel, per-graph LDS)
    csr_build_kernel<<<BG, 1024, 0, stream>>>(src, dst, NOFF, DEG, CSR, NORD);

    // prep all 3 weight sets
    prep_w_kernel<<<dim3(128, 3), 256, 0, stream>>>(W1_rel, W1_root, W2_rel, W2_root,
                                                    W3_rel, W3_root, WT);

    // ---- conv1 (fp32 input cast fused into gemm) ----
    gemm_kernel<1><<<dim3(NN / 128, 2), 256, 0, stream>>>(nullptr, x, nullptr, WT, YB);
    agg_kernel<0><<<BG * 4, 1024, 0, stream>>>(YB, CSR, NOFF, DEG, NORD, b1,
                                               nullptr, nullptr, XB,
                                               nullptr, nullptr, nullptr, nullptr,
                                               XS, 0, 1.f / 1024.f);

    // ---- conv2 (+ fused score partial dots) ----
    gemm_kernel<0><<<dim3(NN / 128, 2), 256, 0, stream>>>(XB, nullptr, nullptr, WT + 32768, YB);
    agg_kernel<1><<<BG * 4, 1024, 0, stream>>>(YB, CSR, NOFF, DEG, NORD, b2,
                                               nullptr, nullptr, X2B,
                                               Ws_rel, Ws_root, SRELP, SROOTP,
                                               XS, 128, 1.f / 1024.f);

    // ---- SAGPooling (score sum + topk + keep-count) ----
    topk_kernel<<<BG, 1024, 0, stream>>>(SRELP, SROOTP, bs, CSR, NOFF, DEG, KEEP, GATE, CNT);

    // ---- conv3 (gate fused into gemm A-staging) ----
    gemm_kernel<2><<<dim3(NN / 128, 2), 256, 0, stream>>>(X2B, nullptr, GATE, WT + 65536, YB);
    agg_kernel<2><<<BG * 4, 1024, 0, stream>>>(YB, CSR, NOFF, DEG, NORD, b3,
                                               KEEP, CNT, nullptr,
                                               nullptr, nullptr, nullptr, nullptr,
                                               XS, 256, 1.f / (float)KKEEP);

    // ---- MLP head ----
    mlp_kernel<<<BG, 512, 0, stream>>>(XS, Wl1, bl1, Wl2, bl2, (float*)d_out);
}

// Round 12
// 200.061 us; speedup vs baseline: 1.2217x; 1.0189x over previous
//
#include <hip/hip_runtime.h>
#include <hip/hip_bf16.h>

#define NN 65536
#define EE 1048576
#define BG 64
#define NPGC 1024
#define KKEEP 820

typedef unsigned short u16;
typedef unsigned int u32;
typedef __attribute__((ext_vector_type(4))) float f32x4;
typedef __attribute__((ext_vector_type(8))) short bf16x8;

__device__ __forceinline__ float bfu_lo(u32 u) {  // low bf16 -> f32
    u32 x = u << 16;
    return __builtin_bit_cast(float, x);
}
__device__ __forceinline__ float bfu_hi(u32 u) {  // high bf16 -> f32
    u32 x = u & 0xffff0000u;
    return __builtin_bit_cast(float, x);
}
__device__ __forceinline__ u16 fbf(float f) {
    __hip_bfloat16 h = __float2bfloat16(f);
    return __builtin_bit_cast(u16, h);
}
__device__ __forceinline__ u32 pack2(float a, float b) {
    return (u32)fbf(a) | ((u32)fbf(b) << 16);
}

// ---------------- CSR build + stable degree-sort order ----------------
// one block per graph. Latency-optimized: all 32 edge loads issued up front
// (registers), shuffle-based scan (2 syncs), hybrid bitonic (shuffle phases
// j<64, LDS only for 10 cross-wave phases).
__global__ __launch_bounds__(1024) void csr_build_kernel(const int* __restrict__ src,
                                                         const int* __restrict__ dst,
                                                         int* __restrict__ noff,
                                                         int* __restrict__ deg,
                                                         int* __restrict__ csr,
                                                         int* __restrict__ nord) {
    __shared__ int hist[NPGC];
    __shared__ int xch[NPGC];
    __shared__ int wsum[16];
    int g = blockIdx.x, t = threadIdx.x;
    int lane = t & 63, wid = t >> 6;
    int ebase = g * 16384;

    // issue all edge loads up front (32 in flight)
    int dv[16], sv[16];
#pragma unroll
    for (int j = 0; j < 16; ++j) dv[j] = dst[ebase + (j << 10) + t] & 1023;
#pragma unroll
    for (int j = 0; j < 16; ++j) sv[j] = src[ebase + (j << 10) + t];

    hist[t] = 0;
    __syncthreads();
#pragma unroll
    for (int j = 0; j < 16; ++j) atomicAdd(&hist[dv[j]], 1);
    __syncthreads();

    int d = hist[t];

    // exclusive scan via wave shfl + cross-wave combine
    int v = d;
#pragma unroll
    for (int s = 1; s < 64; s <<= 1) {
        int u = __shfl_up(v, s, 64);
        if (lane >= s) v += u;
    }
    if (lane == 63) wsum[wid] = v;
    __syncthreads();
    if (t < 16) {
        int w = wsum[t];
#pragma unroll
        for (int s = 1; s < 16; s <<= 1) {
            int u = __shfl_up(w, s, 64);
            if (t >= s) w += u;
        }
        wsum[t] = w;
    }
    __syncthreads();
    int excl = ((wid > 0) ? wsum[wid - 1] : 0) + v - d;

    int node = g * NPGC + t;
    deg[node] = d;
    noff[node] = ebase + excl;
    hist[t] = excl;  // fill cursor
    __syncthreads();

    // fill: 16 independent atomic_rtn -> store chains (pipelined)
#pragma unroll
    for (int j = 0; j < 16; ++j) {
        int p = atomicAdd(&hist[dv[j]], 1);
        csr[ebase + p] = sv[j];
    }

    // stable (deg,id) asc order via hybrid bitonic on unique keys
    int key = (d << 10) | t;
    for (int k = 2; k <= NPGC; k <<= 1) {
        for (int j = k >> 1; j > 0; j >>= 1) {
            int partner;
            if (j >= 64) {
                xch[t] = key;
                __syncthreads();
                partner = xch[t ^ j];
                __syncthreads();
            } else {
                partner = __shfl_xor(key, j, 64);
            }
            bool up = ((t & k) == 0);
            bool lower = ((t & j) == 0);
            int mn = key < partner ? key : partner;
            int mx = key < partner ? partner : key;
            key = (up == lower) ? mn : mx;
        }
    }
    nord[g * NPGC + t] = key & 1023;
}

// WT[l][col][k]: 3 weight sets at once. l = blockIdx.y.
__global__ void prep_w_kernel(const float* __restrict__ Wr1, const float* __restrict__ Wo1,
                              const float* __restrict__ Wr2, const float* __restrict__ Wo2,
                              const float* __restrict__ Wr3, const float* __restrict__ Wo3,
                              u16* __restrict__ WT) {
    int l = blockIdx.y;
    const float* Wrel = l == 0 ? Wr1 : (l == 1 ? Wr2 : Wr3);
    const float* Wroot = l == 0 ? Wo1 : (l == 1 ? Wo2 : Wo3);
    int idx = blockIdx.x * 256 + threadIdx.x;  // 32768
    int col = idx >> 7, k = idx & 127;
    float v = (col < 128) ? Wrel[k * 128 + col] : Wroot[k * 128 + (col - 128)];
    WT[l * 32768 + idx] = fbf(v);
}

// ---------------- GEMM: Y[N][256] = A[N][128] @ Wcat[128][256]  (bf16 MFMA, fp32 acc)
// MODE 0: A = bf16 Xb.  MODE 1: A = fp32 Xf (cast fused, conv1).
// MODE 2: A = bf16 Xb * gate[row] (gate fused, conv3).
template <int MODE>
__global__ __launch_bounds__(256, 2) void gemm_kernel(const u16* __restrict__ Xb,
                                                      const float* __restrict__ Xf,
                                                      const float* __restrict__ gate,
                                                      const u16* __restrict__ WT,
                                                      u16* __restrict__ Y) {
    __shared__ u16 As[128][72];
    __shared__ u16 Bs[128][72];
    int rb = blockIdx.x * 128;
    int cb = blockIdx.y * 128;
    int tid = threadIdx.x;
    int lane = tid & 63, wid = tid >> 6;
    int wr = (wid >> 1) << 6, wc = (wid & 1) << 6;
    int lr = lane & 15, lk = (lane >> 4) << 3;
    f32x4 acc[4][4] = {};

    for (int half = 0; half < 2; ++half) {
        int k0 = half << 6;
        if (half) __syncthreads();
        for (int i = tid; i < 1024; i += 256) {
            int r = i >> 3, c = (i & 7) << 3;
            uint4 av;
            if (MODE == 0) {
                av = *reinterpret_cast<const uint4*>(Xb + (size_t)(rb + r) * 128 + k0 + c);
            } else if (MODE == 1) {
                float4 f0 = *reinterpret_cast<const float4*>(Xf + (size_t)(rb + r) * 128 + k0 + c);
                float4 f1 = *reinterpret_cast<const float4*>(Xf + (size_t)(rb + r) * 128 + k0 + c + 4);
                av.x = pack2(f0.x, f0.y);
                av.y = pack2(f0.z, f0.w);
                av.z = pack2(f1.x, f1.y);
                av.w = pack2(f1.z, f1.w);
            } else {
                float g = gate[rb + r];
                uint4 w = *reinterpret_cast<const uint4*>(Xb + (size_t)(rb + r) * 128 + k0 + c);
                av.x = pack2(bfu_lo(w.x) * g, bfu_hi(w.x) * g);
                av.y = pack2(bfu_lo(w.y) * g, bfu_hi(w.y) * g);
                av.z = pack2(bfu_lo(w.z) * g, bfu_hi(w.z) * g);
                av.w = pack2(bfu_lo(w.w) * g, bfu_hi(w.w) * g);
            }
            *reinterpret_cast<uint4*>(&As[r][c]) = av;
            *reinterpret_cast<uint4*>(&Bs[r][c]) =
                *reinterpret_cast<const uint4*>(WT + (cb + r) * 128 + k0 + c);
        }
        __syncthreads();
        for (int kk = 0; kk < 64; kk += 32) {
            bf16x8 a[4], b[4];
            for (int m = 0; m < 4; ++m)
                a[m] = *reinterpret_cast<const bf16x8*>(&As[wr + m * 16 + lr][kk + lk]);
            for (int n = 0; n < 4; ++n)
                b[n] = *reinterpret_cast<const bf16x8*>(&Bs[wc + n * 16 + lr][kk + lk]);
            for (int m = 0; m < 4; ++m)
                for (int n = 0; n < 4; ++n)
                    acc[m][n] = __builtin_amdgcn_mfma_f32_16x16x32_bf16(a[m], b[n], acc[m][n], 0, 0, 0);
        }
    }
    int orow0 = rb + wr + ((lane >> 4) << 2);
    int ocol0 = cb + wc + (lane & 15);
    for (int m = 0; m < 4; ++m)
        for (int n = 0; n < 4; ++n)
            for (int r = 0; r < 4; ++r)
                Y[(size_t)(orow0 + m * 16 + r) * 256 + ocol0 + n * 16] = fbf(acc[m][n][r]);
}

// ---------------- LDS-staged aggregate + combine + relu + pool (+score) ----------------
// Block = (graph, 32-feature chunk). Stage all 1024 rel-row chunks into LDS
// NODE-MAJOR with pad: sst[node][20 u32] (16 payload + 4 pad, 80 B stride,
// 16B aligned) -> each edge is 4x ds_read_b128 (4x fewer DS instrs than b32),
// row bank-group = 4*(5*node mod 8) spreads all 8 groups. 80 KB LDS, 256
// blocks -> 1 block/CU. pool2 scratch overlays the pad words.
// LAYER 0: conv1 (outb). LAYER 1: conv2 (outb + score partials). LAYER 2: conv3 (keep/cnt).
#define P2IDX(i) ((((i) >> 2) * 20) + 16 + ((i) & 3))
template <int LAYER>
__global__ __launch_bounds__(1024, 4) void agg_kernel(const u16* __restrict__ Y,
                                                      const int* __restrict__ csr,
                                                      const int* __restrict__ noff,
                                                      const int* __restrict__ deg,
                                                      const int* __restrict__ nord,
                                                      const float* __restrict__ bias,
                                                      const float* __restrict__ keep,
                                                      const float* __restrict__ cntg,
                                                      u16* __restrict__ outb,
                                                      const float* __restrict__ wsrel,
                                                      const float* __restrict__ wsroot,
                                                      float* __restrict__ srelp,
                                                      float* __restrict__ srootp,
                                                      float* __restrict__ xs,
                                                      int base, float invdenom) {
    __shared__ u32 sst[20480];  // 1024 rows x 20 u32 = 80 KB
    int g = blockIdx.x >> 2, c = blockIdx.x & 3;
    int t = threadIdx.x;
    int nbase = g * NPGC;

    // stage: thread t loads node t's 64B chunk -> 4 ds_write_b128 (node-major)
    {
        const uint4* sp = reinterpret_cast<const uint4*>(Y + (size_t)(nbase + t) * 256 + c * 32);
        uint4 q0 = sp[0], q1 = sp[1], q2 = sp[2], q3 = sp[3];
        uint4* dp = reinterpret_cast<uint4*>(&sst[t * 20]);
        dp[0] = q0; dp[1] = q1; dp[2] = q2; dp[3] = q3;
    }

    int nloc = nord[nbase + t];
    int node = nbase + nloc;
    int off = noff[node], dg = deg[node];
    float ki = 1.f, cnt;
    if (LAYER == 2) {
        ki = keep[node];
        cnt = cntg[node];
    } else {
        cnt = (float)dg;
    }
    __syncthreads();

    float accL[16] = {0.f, 0.f, 0.f, 0.f, 0.f, 0.f, 0.f, 0.f,
                      0.f, 0.f, 0.f, 0.f, 0.f, 0.f, 0.f, 0.f};
    float accH[16] = {0.f, 0.f, 0.f, 0.f, 0.f, 0.f, 0.f, 0.f,
                      0.f, 0.f, 0.f, 0.f, 0.f, 0.f, 0.f, 0.f};
    if (LAYER != 2 || ki != 0.f) {
        int nbr = (dg > 0) ? (csr[off] & 1023) : 0;
        for (int e = 0; e < dg; ++e) {
            int nxt = (e + 1 < dg) ? (csr[off + e + 1] & 1023) : 0;
            const uint4* qp = reinterpret_cast<const uint4*>(&sst[nbr * 20]);
            uint4 q0 = qp[0], q1 = qp[1], q2 = qp[2], q3 = qp[3];
            u32 vv[16] = {q0.x, q0.y, q0.z, q0.w, q1.x, q1.y, q1.z, q1.w,
                          q2.x, q2.y, q2.z, q2.w, q3.x, q3.y, q3.z, q3.w};
#pragma unroll
            for (int fp = 0; fp < 16; ++fp) {
                accL[fp] += bfu_lo(vv[fp]);
                accH[fp] += bfu_hi(vv[fp]);
            }
            nbr = nxt;
        }
    }

    float inv = ki / fmaxf(cnt, 1.f);
    const uint4* rp = reinterpret_cast<const uint4*>(Y + (size_t)node * 256 + 128 + c * 32);
    uint4 r0 = rp[0], r1 = rp[1], r2 = rp[2], r3 = rp[3];
    u32 rr[16] = {r0.x, r0.y, r0.z, r0.w, r1.x, r1.y, r1.z, r1.w,
                  r2.x, r2.y, r2.z, r2.w, r3.x, r3.y, r3.z, r3.w};
    u32 pk[16];
    float pr = 0.f, po = 0.f;
#pragma unroll
    for (int fp = 0; fp < 16; ++fp) {
        float lo = fmaxf(accL[fp] * inv + bias[c * 32 + 2 * fp] + bfu_lo(rr[fp]), 0.f) * ki;
        float hi = fmaxf(accH[fp] * inv + bias[c * 32 + 2 * fp + 1] + bfu_hi(rr[fp]), 0.f) * ki;
        if (LAYER == 1) {
            pr += lo * wsrel[c * 32 + 2 * fp] + hi * wsrel[c * 32 + 2 * fp + 1];
            po += lo * wsroot[c * 32 + 2 * fp] + hi * wsroot[c * 32 + 2 * fp + 1];
        }
        pk[fp] = pack2(lo, hi);
    }
    if (LAYER != 2) {
        uint4* op = reinterpret_cast<uint4*>(outb + (size_t)node * 128 + c * 32);
        uint4 o0 = {pk[0], pk[1], pk[2], pk[3]};
        uint4 o1 = {pk[4], pk[5], pk[6], pk[7]};
        uint4 o2 = {pk[8], pk[9], pk[10], pk[11]};
        uint4 o3 = {pk[12], pk[13], pk[14], pk[15]};
        op[0] = o0; op[1] = o1; op[2] = o2; op[3] = o3;
    }
    if (LAYER == 1) {
        srelp[(size_t)c * NN + node] = pr;
        srootp[(size_t)c * NN + node] = po;
    }

    __syncthreads();  // all LDS gathers done; reuse sst rows for pool values
    {
        uint4* dp = reinterpret_cast<uint4*>(&sst[t * 20]);
        uint4 o0 = {pk[0], pk[1], pk[2], pk[3]};
        uint4 o1 = {pk[4], pk[5], pk[6], pk[7]};
        uint4 o2 = {pk[8], pk[9], pk[10], pk[11]};
        uint4 o3 = {pk[12], pk[13], pk[14], pk[15]};
        dp[0] = o0; dp[1] = o1; dp[2] = o2; dp[3] = o3;
    }
    __syncthreads();

    // pool reduce: f = feature in chunk, sub = node class mod 32; partials in pads
    {
        int f = t >> 5, sub = t & 31;
        float s = 0.f;
#pragma unroll 4
        for (int k = 0; k < 32; ++k) {
            u32 v = sst[(sub + 32 * k) * 20 + (f >> 1)];
            s += (f & 1) ? bfu_hi(v) : bfu_lo(v);
        }
        sst[P2IDX(f * 33 + sub)] = __builtin_bit_cast(u32, s);
    }
    __syncthreads();
    if (t < 32) {
        float s = 0.f;
#pragma unroll 4
        for (int sub = 0; sub < 32; ++sub)
            s += __builtin_bit_cast(float, sst[P2IDX(t * 33 + sub)]);
        xs[g * 384 + base + c * 32 + t] = s * invdenom;
    }
}

// ---------------- per-graph top-K (score sum + bitonic sort + keep-count) ----------------
__global__ __launch_bounds__(1024) void topk_kernel(const float* __restrict__ srelp,
                                                    const float* __restrict__ srootp,
                                                    const float* __restrict__ bs,
                                                    const int* __restrict__ csr,
                                                    const int* __restrict__ noff,
                                                    const int* __restrict__ deg,
                                                    float* __restrict__ keep,
                                                    float* __restrict__ gate,
                                                    float* __restrict__ cntg) {
    __shared__ float sc[NPGC];
    __shared__ int si[NPGC];
    __shared__ float ssr[NPGC];
    int g = blockIdx.x, t = threadIdx.x;
    int node = g * NPGC + t;
    // fixed-order sum of the 4 chunk partials (deterministic)
    ssr[t] = srelp[node] + srelp[NN + node] + srelp[2 * NN + node] + srelp[3 * NN + node];
    float sroot = srootp[node] + srootp[NN + node] + srootp[2 * NN + node] + srootp[3 * NN + node];
    __syncthreads();
    int off = noff[node], dg = deg[node];
    float s = 0.f;
    for (int e = 0; e < dg; ++e) s += ssr[csr[off + e] & 1023];
    sc[t] = s / fmaxf((float)dg, 1.0f) + bs[0] + sroot;
    si[t] = t;
    __syncthreads();
    for (int k = 2; k <= NPGC; k <<= 1) {
        for (int j = k >> 1; j > 0; j >>= 1) {
            int ixj = t ^ j;
            if (ixj > t) {
                float a = sc[t], b = sc[ixj];
                int ai = si[t], bi = si[ixj];
                bool less = (a > b) || (a == b && ai < bi);  // desc, idx-asc tiebreak
                bool up = ((t & k) == 0);
                if (less != up) { sc[t] = b; sc[ixj] = a; si[t] = bi; si[ixj] = ai; }
            }
            __syncthreads();
        }
    }
    int oloc = si[t];
    float kf = (t < KKEEP) ? 1.f : 0.f;
    keep[g * NPGC + oloc] = kf;
    gate[g * NPGC + oloc] = kf * tanhf(sc[t]);
    ssr[oloc] = kf;  // reuse as keep flags
    __syncthreads();
    // conv3 neighbor keep-count
    float cnt = 0.f;
    for (int e = 0; e < dg; ++e) cnt += ssr[csr[off + e] & 1023];
    cntg[node] = cnt;
}

// ---------------- MLP head + log_softmax; one block of 512 per graph.
__global__ __launch_bounds__(512) void mlp_kernel(const float* __restrict__ xs,
                                                  const float* __restrict__ Wl1,
                                                  const float* __restrict__ bl1,
                                                  const float* __restrict__ Wl2,
                                                  const float* __restrict__ bl2,
                                                  float* __restrict__ out) {
    __shared__ float xsl[384];
    __shared__ float part[4][128];
    __shared__ float wl2s[1280];
    __shared__ float wred[2][10];
    __shared__ float lgs[10];
    int g = blockIdx.x, tid = threadIdx.x;
    int t = tid & 127, kg = tid >> 7;

    for (int i = tid; i < 1280; i += 512) wl2s[i] = Wl2[i];
    if (tid < 384) xsl[tid] = xs[g * 384 + tid];
    __syncthreads();

    float p = 0.f;
    int k0 = kg * 96;
#pragma unroll 8
    for (int k = 0; k < 96; ++k) p += xsl[k0 + k] * Wl1[(k0 + k) * 128 + t];
    part[kg][t] = p;
    __syncthreads();

    if (tid < 128) {
        float h = fmaxf(bl1[t] + part[0][t] + part[1][t] + part[2][t] + part[3][t], 0.f);
        float pc[10];
#pragma unroll
        for (int c = 0; c < 10; ++c) pc[c] = h * wl2s[t * 10 + c];
#pragma unroll
        for (int d = 1; d < 64; d <<= 1) {
#pragma unroll
            for (int c = 0; c < 10; ++c) pc[c] += __shfl_xor(pc[c], d, 64);
        }
        if ((t & 63) == 0) {
#pragma unroll
            for (int c = 0; c < 10; ++c) wred[t >> 6][c] = pc[c];
        }
    }
    __syncthreads();
    if (tid < 10) lgs[tid] = wred[0][tid] + wred[1][tid] + bl2[tid];
    __syncthreads();
    if (tid < 10) {
        float m = lgs[0];
#pragma unroll
        for (int c = 1; c < 10; ++c) m = fmaxf(m, lgs[c]);
        float s = 0.f;
#pragma unroll
        for (int c = 0; c < 10; ++c) s += expf(lgs[c] - m);
        out[g * 10 + tid] = lgs[tid] - m - logf(s);
    }
}

extern "C" void kernel_launch(void* const* d_in, const int* in_sizes, int n_in,
                              void* d_out, int out_size, void* d_ws, size_t ws_size,
                              hipStream_t stream) {
    const float* x       = (const float*)d_in[0];
    const int*   src     = (const int*)d_in[1];
    const int*   dst     = (const int*)d_in[2];
    const float* W1_rel  = (const float*)d_in[3];
    const float* b1      = (const float*)d_in[4];
    const float* W1_root = (const float*)d_in[5];
    const float* W2_rel  = (const float*)d_in[6];
    const float* b2      = (const float*)d_in[7];
    const float* W2_root = (const float*)d_in[8];
    const float* W3_rel  = (const float*)d_in[9];
    const float* b3      = (const float*)d_in[10];
    const float* W3_root = (const float*)d_in[11];
    const float* Ws_rel  = (const float*)d_in[12];
    const float* bs      = (const float*)d_in[13];
    const float* Ws_root = (const float*)d_in[14];
    const float* Wl1     = (const float*)d_in[15];
    const float* bl1     = (const float*)d_in[16];
    const float* Wl2     = (const float*)d_in[17];
    const float* bl2     = (const float*)d_in[18];

    char* ws = (char*)d_ws;
    size_t off = 0;
    auto alloc = [&](size_t bytes) -> void* {
        void* p = ws + off;
        off += (bytes + 255) & ~(size_t)255;
        return p;
    };
    u16*   XB     = (u16*)alloc((size_t)NN * 128 * 2);   // conv1 agg output / conv2 input
    u16*   X2B    = (u16*)alloc((size_t)NN * 128 * 2);   // conv2 output (pre-gate)
    u16*   YB     = (u16*)alloc((size_t)NN * 256 * 2);   // gemm output (rel|root)
    u16*   WT     = (u16*)alloc(3 * 256 * 128 * 2);      // 3 weight sets
    float* SRELP  = (float*)alloc((size_t)4 * NN * 4);   // per-chunk score partials
    float* SROOTP = (float*)alloc((size_t)4 * NN * 4);
    float* GATE   = (float*)alloc(NN * 4);
    float* KEEP   = (float*)alloc(NN * 4);
    float* CNT    = (float*)alloc(NN * 4);               // conv3 neighbor keep-count
    int*   DEG    = (int*)alloc(NN * 4);
    int*   NOFF   = (int*)alloc(NN * 4);
    int*   NORD   = (int*)alloc(NN * 4);                 // degree-sorted node order
    int*   CSR    = (int*)alloc((size_t)EE * 4);
    float* XS     = (float*)alloc((size_t)BG * 384 * 4); // pool outputs (exclusive stores)
    (void)ws_size; (void)n_in; (void)in_sizes; (void)out_size;

    // CSR build + degree-sort order (single kernel, per-graph LDS)
    csr_build_kernel<<<BG, 1024, 0, stream>>>(src, dst, NOFF, DEG, CSR, NORD);

    // prep all 3 weight sets
    prep_w_kernel<<<dim3(128, 3), 256, 0, stream>>>(W1_rel, W1_root, W2_rel, W2_root,
                                                    W3_rel, W3_root, WT);

    // ---- conv1 (fp32 input cast fused into gemm) ----
    gemm_kernel<1><<<dim3(NN / 128, 2), 256, 0, stream>>>(nullptr, x, nullptr, WT, YB);
    agg_kernel<0><<<BG * 4, 1024, 0, stream>>>(YB, CSR, NOFF, DEG, NORD, b1,
                                               nullptr, nullptr, XB,
                                               nullptr, nullptr, nullptr, nullptr,
                                               XS, 0, 1.f / 1024.f);

    // ---- conv2 (+ fused score partial dots) ----
    gemm_kernel<0><<<dim3(NN / 128, 2), 256, 0, stream>>>(XB, nullptr, nullptr, WT + 32768, YB);
    agg_kernel<1><<<BG * 4, 1024, 0, stream>>>(YB, CSR, NOFF, DEG, NORD, b2,
                                               nullptr, nullptr, X2B,
                                               Ws_rel, Ws_root, SRELP, SROOTP,
                                               XS, 128, 1.f / 1024.f);

    // ---- SAGPooling (score sum + topk + keep-count) ----
    topk_kernel<<<BG, 1024, 0, stream>>>(SRELP, SROOTP, bs, CSR, NOFF, DEG, KEEP, GATE, CNT);

    // ---- conv3 (gate fused into gemm A-staging) ----
    gemm_kernel<2><<<dim3(NN / 128, 2), 256, 0, stream>>>(X2B, nullptr, GATE, WT + 65536, YB);
    agg_kernel<2><<<BG * 4, 1024, 0, stream>>>(YB, CSR, NOFF, DEG, NORD, b3,
                                               KEEP, CNT, nullptr,
                                               nullptr, nullptr, nullptr, nullptr,
                                               XS, 256, 1.f / (float)KKEEP);

    // ---- MLP head ----
    mlp_kernel<<<BG, 512, 0, stream>>>(XS, Wl1, bl1, Wl2, bl2, (float*)d_out);
}

// Round 13
// 169.603 us; speedup vs baseline: 1.4411x; 1.1796x over previous
//
#include <hip/hip_runtime.h>
#include <hip/hip_bf16.h>

#define NN 65536
#define EE 1048576
#define BG 64
#define NPGC 1024
#define KKEEP 820

typedef unsigned short u16;
typedef unsigned int u32;
typedef __attribute__((ext_vector_type(4))) float f32x4;
typedef __attribute__((ext_vector_type(8))) short bf16x8;

__device__ __forceinline__ float bfu_lo(u32 u) {  // low bf16 -> f32
    u32 x = u << 16;
    return __builtin_bit_cast(float, x);
}
__device__ __forceinline__ float bfu_hi(u32 u) {  // high bf16 -> f32
    u32 x = u & 0xffff0000u;
    return __builtin_bit_cast(float, x);
}
__device__ __forceinline__ u16 fbf(float f) {
    __hip_bfloat16 h = __float2bfloat16(f);
    return __builtin_bit_cast(u16, h);
}
__device__ __forceinline__ u32 pack2(float a, float b) {
    return (u32)fbf(a) | ((u32)fbf(b) << 16);
}

// ---------------- CSR build + stable degree-sort order ----------------
// one block per graph. All 32 edge loads issued up front, shuffle scan,
// hybrid bitonic sort. CSR stored as u16 LOCAL ids (LDS-stageable downstream).
__global__ __launch_bounds__(1024) void csr_build_kernel(const int* __restrict__ src,
                                                         const int* __restrict__ dst,
                                                         int* __restrict__ noff,
                                                         int* __restrict__ deg,
                                                         u16* __restrict__ csr16,
                                                         int* __restrict__ nord) {
    __shared__ int hist[NPGC];
    __shared__ int xch[NPGC];
    __shared__ int wsum[16];
    int g = blockIdx.x, t = threadIdx.x;
    int lane = t & 63, wid = t >> 6;
    int ebase = g * 16384;

    // issue all edge loads up front (32 in flight)
    int dv[16], sv[16];
#pragma unroll
    for (int j = 0; j < 16; ++j) dv[j] = dst[ebase + (j << 10) + t] & 1023;
#pragma unroll
    for (int j = 0; j < 16; ++j) sv[j] = src[ebase + (j << 10) + t];

    hist[t] = 0;
    __syncthreads();
#pragma unroll
    for (int j = 0; j < 16; ++j) atomicAdd(&hist[dv[j]], 1);
    __syncthreads();

    int d = hist[t];

    // exclusive scan via wave shfl + cross-wave combine
    int v = d;
#pragma unroll
    for (int s = 1; s < 64; s <<= 1) {
        int u = __shfl_up(v, s, 64);
        if (lane >= s) v += u;
    }
    if (lane == 63) wsum[wid] = v;
    __syncthreads();
    if (t < 16) {
        int w = wsum[t];
#pragma unroll
        for (int s = 1; s < 16; s <<= 1) {
            int u = __shfl_up(w, s, 64);
            if (t >= s) w += u;
        }
        wsum[t] = w;
    }
    __syncthreads();
    int excl = ((wid > 0) ? wsum[wid - 1] : 0) + v - d;

    int node = g * NPGC + t;
    deg[node] = d;
    noff[node] = ebase + excl;
    hist[t] = excl;  // fill cursor
    __syncthreads();

    // fill: 16 independent atomic_rtn -> store chains (pipelined)
#pragma unroll
    for (int j = 0; j < 16; ++j) {
        int p = atomicAdd(&hist[dv[j]], 1);
        csr16[ebase + p] = (u16)(sv[j] & 1023);
    }

    // stable (deg,id) asc order via hybrid bitonic on unique keys
    int key = (d << 10) | t;
    for (int k = 2; k <= NPGC; k <<= 1) {
        for (int j = k >> 1; j > 0; j >>= 1) {
            int partner;
            if (j >= 64) {
                xch[t] = key;
                __syncthreads();
                partner = xch[t ^ j];
                __syncthreads();
            } else {
                partner = __shfl_xor(key, j, 64);
            }
            bool up = ((t & k) == 0);
            bool lower = ((t & j) == 0);
            int mn = key < partner ? key : partner;
            int mx = key < partner ? partner : key;
            key = (up == lower) ? mn : mx;
        }
    }
    nord[g * NPGC + t] = key & 1023;
}

// WT[l][col][k]: 3 weight sets at once. l = blockIdx.y.
__global__ void prep_w_kernel(const float* __restrict__ Wr1, const float* __restrict__ Wo1,
                              const float* __restrict__ Wr2, const float* __restrict__ Wo2,
                              const float* __restrict__ Wr3, const float* __restrict__ Wo3,
                              u16* __restrict__ WT) {
    int l = blockIdx.y;
    const float* Wrel = l == 0 ? Wr1 : (l == 1 ? Wr2 : Wr3);
    const float* Wroot = l == 0 ? Wo1 : (l == 1 ? Wo2 : Wo3);
    int idx = blockIdx.x * 256 + threadIdx.x;  // 32768
    int col = idx >> 7, k = idx & 127;
    float v = (col < 128) ? Wrel[k * 128 + col] : Wroot[k * 128 + (col - 128)];
    WT[l * 32768 + idx] = fbf(v);
}

// ---------------- GEMM: Y[N][256] = A[N][128] @ Wcat[128][256]  (bf16 MFMA, fp32 acc)
// MODE 0: A = bf16 Xb.  MODE 1: A = fp32 Xf (cast fused, conv1).
// MODE 2: A = bf16 Xb * gate[row] (gate fused, conv3).
template <int MODE>
__global__ __launch_bounds__(256, 2) void gemm_kernel(const u16* __restrict__ Xb,
                                                      const float* __restrict__ Xf,
                                                      const float* __restrict__ gate,
                                                      const u16* __restrict__ WT,
                                                      u16* __restrict__ Y) {
    __shared__ u16 As[128][72];
    __shared__ u16 Bs[128][72];
    int rb = blockIdx.x * 128;
    int cb = blockIdx.y * 128;
    int tid = threadIdx.x;
    int lane = tid & 63, wid = tid >> 6;
    int wr = (wid >> 1) << 6, wc = (wid & 1) << 6;
    int lr = lane & 15, lk = (lane >> 4) << 3;
    f32x4 acc[4][4] = {};

    for (int half = 0; half < 2; ++half) {
        int k0 = half << 6;
        if (half) __syncthreads();
        for (int i = tid; i < 1024; i += 256) {
            int r = i >> 3, c = (i & 7) << 3;
            uint4 av;
            if (MODE == 0) {
                av = *reinterpret_cast<const uint4*>(Xb + (size_t)(rb + r) * 128 + k0 + c);
            } else if (MODE == 1) {
                float4 f0 = *reinterpret_cast<const float4*>(Xf + (size_t)(rb + r) * 128 + k0 + c);
                float4 f1 = *reinterpret_cast<const float4*>(Xf + (size_t)(rb + r) * 128 + k0 + c + 4);
                av.x = pack2(f0.x, f0.y);
                av.y = pack2(f0.z, f0.w);
                av.z = pack2(f1.x, f1.y);
                av.w = pack2(f1.z, f1.w);
            } else {
                float g = gate[rb + r];
                uint4 w = *reinterpret_cast<const uint4*>(Xb + (size_t)(rb + r) * 128 + k0 + c);
                av.x = pack2(bfu_lo(w.x) * g, bfu_hi(w.x) * g);
                av.y = pack2(bfu_lo(w.y) * g, bfu_hi(w.y) * g);
                av.z = pack2(bfu_lo(w.z) * g, bfu_hi(w.z) * g);
                av.w = pack2(bfu_lo(w.w) * g, bfu_hi(w.w) * g);
            }
            *reinterpret_cast<uint4*>(&As[r][c]) = av;
            *reinterpret_cast<uint4*>(&Bs[r][c]) =
                *reinterpret_cast<const uint4*>(WT + (cb + r) * 128 + k0 + c);
        }
        __syncthreads();
        for (int kk = 0; kk < 64; kk += 32) {
            bf16x8 a[4], b[4];
            for (int m = 0; m < 4; ++m)
                a[m] = *reinterpret_cast<const bf16x8*>(&As[wr + m * 16 + lr][kk + lk]);
            for (int n = 0; n < 4; ++n)
                b[n] = *reinterpret_cast<const bf16x8*>(&Bs[wc + n * 16 + lr][kk + lk]);
            for (int m = 0; m < 4; ++m)
                for (int n = 0; n < 4; ++n)
                    acc[m][n] = __builtin_amdgcn_mfma_f32_16x16x32_bf16(a[m], b[n], acc[m][n], 0, 0, 0);
        }
    }
    int orow0 = rb + wr + ((lane >> 4) << 2);
    int ocol0 = cb + wc + (lane & 15);
    for (int m = 0; m < 4; ++m)
        for (int n = 0; n < 4; ++n)
            for (int r = 0; r < 4; ++r)
                Y[(size_t)(orow0 + m * 16 + r) * 256 + ocol0 + n * 16] = fbf(acc[m][n][r]);
}

// ---------------- LDS-staged aggregate + combine + relu + pool (+score) ----------------
// Block = (graph, 32-feature chunk). Features staged node-major padded
// (sst[node][20 u32], 4x ds_read_b128 per edge); CSR16 staged in LDS too ->
// the edge loop is pure LDS (no global ops on the critical path).
// LAYER 0: conv1 (outb). LAYER 1: conv2 (outb + score partials). LAYER 2: conv3 (keep/cnt).
#define P2IDX(i) ((((i) >> 2) * 20) + 16 + ((i) & 3))
template <int LAYER>
__global__ __launch_bounds__(1024, 4) void agg_kernel(const u16* __restrict__ Y,
                                                      const u16* __restrict__ csr16,
                                                      const int* __restrict__ noff,
                                                      const int* __restrict__ deg,
                                                      const int* __restrict__ nord,
                                                      const float* __restrict__ bias,
                                                      const float* __restrict__ keep,
                                                      const float* __restrict__ cntg,
                                                      u16* __restrict__ outb,
                                                      const float* __restrict__ wsrel,
                                                      const float* __restrict__ wsroot,
                                                      float* __restrict__ srelp,
                                                      float* __restrict__ srootp,
                                                      float* __restrict__ xs,
                                                      int base, float invdenom) {
    __shared__ u32 sst[20480];     // 1024 rows x 20 u32 = 80 KB
    __shared__ u16 csr_s[16384];   // this graph's edge list (local ids), 32 KB
    int g = blockIdx.x >> 2, c = blockIdx.x & 3;
    int t = threadIdx.x;
    int nbase = g * NPGC;

    // stage features: thread t loads node t's 64B chunk -> 4 ds_write_b128
    {
        const uint4* sp = reinterpret_cast<const uint4*>(Y + (size_t)(nbase + t) * 256 + c * 32);
        uint4 q0 = sp[0], q1 = sp[1], q2 = sp[2], q3 = sp[3];
        uint4* dp = reinterpret_cast<uint4*>(&sst[t * 20]);
        dp[0] = q0; dp[1] = q1; dp[2] = q2; dp[3] = q3;
    }
    // stage edge list: 32 KB coalesced (2 uint4 per thread)
    {
        const uint4* cp = reinterpret_cast<const uint4*>(csr16 + ((size_t)g << 14));
        uint4* cd = reinterpret_cast<uint4*>(csr_s);
        cd[t] = cp[t];
        cd[t + 1024] = cp[t + 1024];
    }

    int nloc = nord[nbase + t];
    int node = nbase + nloc;
    int offl = noff[node] - (g << 14), dg = deg[node];
    float ki = 1.f, cnt;
    if (LAYER == 2) {
        ki = keep[node];
        cnt = cntg[node];
    } else {
        cnt = (float)dg;
    }
    __syncthreads();

    float accL[16] = {0.f, 0.f, 0.f, 0.f, 0.f, 0.f, 0.f, 0.f,
                      0.f, 0.f, 0.f, 0.f, 0.f, 0.f, 0.f, 0.f};
    float accH[16] = {0.f, 0.f, 0.f, 0.f, 0.f, 0.f, 0.f, 0.f,
                      0.f, 0.f, 0.f, 0.f, 0.f, 0.f, 0.f, 0.f};
    if (LAYER != 2 || ki != 0.f) {
        int nbr = (dg > 0) ? csr_s[offl] : 0;
        for (int e = 0; e < dg; ++e) {
            int nxt = (e + 1 < dg) ? csr_s[offl + e + 1] : 0;
            const uint4* qp = reinterpret_cast<const uint4*>(&sst[nbr * 20]);
            uint4 q0 = qp[0], q1 = qp[1], q2 = qp[2], q3 = qp[3];
            u32 vv[16] = {q0.x, q0.y, q0.z, q0.w, q1.x, q1.y, q1.z, q1.w,
                          q2.x, q2.y, q2.z, q2.w, q3.x, q3.y, q3.z, q3.w};
#pragma unroll
            for (int fp = 0; fp < 16; ++fp) {
                accL[fp] += bfu_lo(vv[fp]);
                accH[fp] += bfu_hi(vv[fp]);
            }
            nbr = nxt;
        }
    }

    float inv = ki / fmaxf(cnt, 1.f);
    const uint4* rp = reinterpret_cast<const uint4*>(Y + (size_t)node * 256 + 128 + c * 32);
    uint4 r0 = rp[0], r1 = rp[1], r2 = rp[2], r3 = rp[3];
    u32 rr[16] = {r0.x, r0.y, r0.z, r0.w, r1.x, r1.y, r1.z, r1.w,
                  r2.x, r2.y, r2.z, r2.w, r3.x, r3.y, r3.z, r3.w};
    u32 pk[16];
    float pr = 0.f, po = 0.f;
#pragma unroll
    for (int fp = 0; fp < 16; ++fp) {
        float lo = fmaxf(accL[fp] * inv + bias[c * 32 + 2 * fp] + bfu_lo(rr[fp]), 0.f) * ki;
        float hi = fmaxf(accH[fp] * inv + bias[c * 32 + 2 * fp + 1] + bfu_hi(rr[fp]), 0.f) * ki;
        if (LAYER == 1) {
            pr += lo * wsrel[c * 32 + 2 * fp] + hi * wsrel[c * 32 + 2 * fp + 1];
            po += lo * wsroot[c * 32 + 2 * fp] + hi * wsroot[c * 32 + 2 * fp + 1];
        }
        pk[fp] = pack2(lo, hi);
    }
    if (LAYER != 2) {
        uint4* op = reinterpret_cast<uint4*>(outb + (size_t)node * 128 + c * 32);
        uint4 o0 = {pk[0], pk[1], pk[2], pk[3]};
        uint4 o1 = {pk[4], pk[5], pk[6], pk[7]};
        uint4 o2 = {pk[8], pk[9], pk[10], pk[11]};
        uint4 o3 = {pk[12], pk[13], pk[14], pk[15]};
        op[0] = o0; op[1] = o1; op[2] = o2; op[3] = o3;
    }
    if (LAYER == 1) {
        srelp[(size_t)c * NN + node] = pr;
        srootp[(size_t)c * NN + node] = po;
    }

    __syncthreads();  // all LDS gathers done; reuse sst rows for pool values
    {
        uint4* dp = reinterpret_cast<uint4*>(&sst[t * 20]);
        uint4 o0 = {pk[0], pk[1], pk[2], pk[3]};
        uint4 o1 = {pk[4], pk[5], pk[6], pk[7]};
        uint4 o2 = {pk[8], pk[9], pk[10], pk[11]};
        uint4 o3 = {pk[12], pk[13], pk[14], pk[15]};
        dp[0] = o0; dp[1] = o1; dp[2] = o2; dp[3] = o3;
    }
    __syncthreads();

    // pool reduce: f = feature in chunk, sub = node class mod 32; partials in pads
    {
        int f = t >> 5, sub = t & 31;
        float s = 0.f;
#pragma unroll 4
        for (int k = 0; k < 32; ++k) {
            u32 v = sst[(sub + 32 * k) * 20 + (f >> 1)];
            s += (f & 1) ? bfu_hi(v) : bfu_lo(v);
        }
        sst[P2IDX(f * 33 + sub)] = __builtin_bit_cast(u32, s);
    }
    __syncthreads();
    if (t < 32) {
        float s = 0.f;
#pragma unroll 4
        for (int sub = 0; sub < 32; ++sub)
            s += __builtin_bit_cast(float, sst[P2IDX(t * 33 + sub)]);
        xs[g * 384 + base + c * 32 + t] = s * invdenom;
    }
}

// ---------------- per-graph top-K (score sum + bitonic sort + keep-count) ----------------
__global__ __launch_bounds__(1024) void topk_kernel(const float* __restrict__ srelp,
                                                    const float* __restrict__ srootp,
                                                    const float* __restrict__ bs,
                                                    const u16* __restrict__ csr16,
                                                    const int* __restrict__ noff,
                                                    const int* __restrict__ deg,
                                                    float* __restrict__ keep,
                                                    float* __restrict__ gate,
                                                    float* __restrict__ cntg) {
    __shared__ float sc[NPGC];
    __shared__ int si[NPGC];
    __shared__ float ssr[NPGC];
    __shared__ u16 csr_s[16384];
    int g = blockIdx.x, t = threadIdx.x;
    int node = g * NPGC + t;
    // stage edge list (32 KB coalesced)
    {
        const uint4* cp = reinterpret_cast<const uint4*>(csr16 + ((size_t)g << 14));
        uint4* cd = reinterpret_cast<uint4*>(csr_s);
        cd[t] = cp[t];
        cd[t + 1024] = cp[t + 1024];
    }
    // fixed-order sum of the 4 chunk partials (deterministic)
    ssr[t] = srelp[node] + srelp[NN + node] + srelp[2 * NN + node] + srelp[3 * NN + node];
    float sroot = srootp[node] + srootp[NN + node] + srootp[2 * NN + node] + srootp[3 * NN + node];
    __syncthreads();
    int offl = noff[node] - (g << 14), dg = deg[node];
    float s = 0.f;
    for (int e = 0; e < dg; ++e) s += ssr[csr_s[offl + e]];
    sc[t] = s / fmaxf((float)dg, 1.0f) + bs[0] + sroot;
    si[t] = t;
    __syncthreads();
    for (int k = 2; k <= NPGC; k <<= 1) {
        for (int j = k >> 1; j > 0; j >>= 1) {
            int ixj = t ^ j;
            if (ixj > t) {
                float a = sc[t], b = sc[ixj];
                int ai = si[t], bi = si[ixj];
                bool less = (a > b) || (a == b && ai < bi);  // desc, idx-asc tiebreak
                bool up = ((t & k) == 0);
                if (less != up) { sc[t] = b; sc[ixj] = a; si[t] = bi; si[ixj] = ai; }
            }
            __syncthreads();
        }
    }
    int oloc = si[t];
    float kf = (t < KKEEP) ? 1.f : 0.f;
    keep[g * NPGC + oloc] = kf;
    gate[g * NPGC + oloc] = kf * tanhf(sc[t]);
    ssr[oloc] = kf;  // reuse as keep flags
    __syncthreads();
    // conv3 neighbor keep-count
    float cnt = 0.f;
    for (int e = 0; e < dg; ++e) cnt += ssr[csr_s[offl + e]];
    cntg[node] = cnt;
}

// ---------------- MLP head + log_softmax; one block of 512 per graph.
__global__ __launch_bounds__(512) void mlp_kernel(const float* __restrict__ xs,
                                                  const float* __restrict__ Wl1,
                                                  const float* __restrict__ bl1,
                                                  const float* __restrict__ Wl2,
                                                  const float* __restrict__ bl2,
                                                  float* __restrict__ out) {
    __shared__ float xsl[384];
    __shared__ float part[4][128];
    __shared__ float wl2s[1280];
    __shared__ float wred[2][10];
    __shared__ float lgs[10];
    int g = blockIdx.x, tid = threadIdx.x;
    int t = tid & 127, kg = tid >> 7;

    for (int i = tid; i < 1280; i += 512) wl2s[i] = Wl2[i];
    if (tid < 384) xsl[tid] = xs[g * 384 + tid];
    __syncthreads();

    float p = 0.f;
    int k0 = kg * 96;
#pragma unroll 8
    for (int k = 0; k < 96; ++k) p += xsl[k0 + k] * Wl1[(k0 + k) * 128 + t];
    part[kg][t] = p;
    __syncthreads();

    if (tid < 128) {
        float h = fmaxf(bl1[t] + part[0][t] + part[1][t] + part[2][t] + part[3][t], 0.f);
        float pc[10];
#pragma unroll
        for (int c = 0; c < 10; ++c) pc[c] = h * wl2s[t * 10 + c];
#pragma unroll
        for (int d = 1; d < 64; d <<= 1) {
#pragma unroll
            for (int c = 0; c < 10; ++c) pc[c] += __shfl_xor(pc[c], d, 64);
        }
        if ((t & 63) == 0) {
#pragma unroll
            for (int c = 0; c < 10; ++c) wred[t >> 6][c] = pc[c];
        }
    }
    __syncthreads();
    if (tid < 10) lgs[tid] = wred[0][tid] + wred[1][tid] + bl2[tid];
    __syncthreads();
    if (tid < 10) {
        float m = lgs[0];
#pragma unroll
        for (int c = 1; c < 10; ++c) m = fmaxf(m, lgs[c]);
        float s = 0.f;
#pragma unroll
        for (int c = 0; c < 10; ++c) s += expf(lgs[c] - m);
        out[g * 10 + tid] = lgs[tid] - m - logf(s);
    }
}

extern "C" void kernel_launch(void* const* d_in, const int* in_sizes, int n_in,
                              void* d_out, int out_size, void* d_ws, size_t ws_size,
                              hipStream_t stream) {
    const float* x       = (const float*)d_in[0];
    const int*   src     = (const int*)d_in[1];
    const int*   dst     = (const int*)d_in[2];
    const float* W1_rel  = (const float*)d_in[3];
    const float* b1      = (const float*)d_in[4];
    const float* W1_root = (const float*)d_in[5];
    const float* W2_rel  = (const float*)d_in[6];
    const float* b2      = (const float*)d_in[7];
    const float* W2_root = (const float*)d_in[8];
    const float* W3_rel  = (const float*)d_in[9];
    const float* b3      = (const float*)d_in[10];
    const float* W3_root = (const float*)d_in[11];
    const float* Ws_rel  = (const float*)d_in[12];
    const float* bs      = (const float*)d_in[13];
    const float* Ws_root = (const float*)d_in[14];
    const float* Wl1     = (const float*)d_in[15];
    const float* bl1     = (const float*)d_in[16];
    const float* Wl2     = (const float*)d_in[17];
    const float* bl2     = (const float*)d_in[18];

    char* ws = (char*)d_ws;
    size_t off = 0;
    auto alloc = [&](size_t bytes) -> void* {
        void* p = ws + off;
        off += (bytes + 255) & ~(size_t)255;
        return p;
    };
    u16*   XB     = (u16*)alloc((size_t)NN * 128 * 2);   // conv1 agg output / conv2 input
    u16*   X2B    = (u16*)alloc((size_t)NN * 128 * 2);   // conv2 output (pre-gate)
    u16*   YB     = (u16*)alloc((size_t)NN * 256 * 2);   // gemm output (rel|root)
    u16*   WT     = (u16*)alloc(3 * 256 * 128 * 2);      // 3 weight sets
    float* SRELP  = (float*)alloc((size_t)4 * NN * 4);   // per-chunk score partials
    float* SROOTP = (float*)alloc((size_t)4 * NN * 4);
    float* GATE   = (float*)alloc(NN * 4);
    float* KEEP   = (float*)alloc(NN * 4);
    float* CNT    = (float*)alloc(NN * 4);               // conv3 neighbor keep-count
    int*   DEG    = (int*)alloc(NN * 4);
    int*   NOFF   = (int*)alloc(NN * 4);
    int*   NORD   = (int*)alloc(NN * 4);                 // degree-sorted node order
    u16*   CSR16  = (u16*)alloc((size_t)EE * 2);         // edge list, u16 local ids
    float* XS     = (float*)alloc((size_t)BG * 384 * 4); // pool outputs (exclusive stores)
    (void)ws_size; (void)n_in; (void)in_sizes; (void)out_size;

    // CSR build + degree-sort order (single kernel, per-graph LDS)
    csr_build_kernel<<<BG, 1024, 0, stream>>>(src, dst, NOFF, DEG, CSR16, NORD);

    // prep all 3 weight sets
    prep_w_kernel<<<dim3(128, 3), 256, 0, stream>>>(W1_rel, W1_root, W2_rel, W2_root,
                                                    W3_rel, W3_root, WT);

    // ---- conv1 (fp32 input cast fused into gemm) ----
    gemm_kernel<1><<<dim3(NN / 128, 2), 256, 0, stream>>>(nullptr, x, nullptr, WT, YB);
    agg_kernel<0><<<BG * 4, 1024, 0, stream>>>(YB, CSR16, NOFF, DEG, NORD, b1,
                                               nullptr, nullptr, XB,
                                               nullptr, nullptr, nullptr, nullptr,
                                               XS, 0, 1.f / 1024.f);

    // ---- conv2 (+ fused score partial dots) ----
    gemm_kernel<0><<<dim3(NN / 128, 2), 256, 0, stream>>>(XB, nullptr, nullptr, WT + 32768, YB);
    agg_kernel<1><<<BG * 4, 1024, 0, stream>>>(YB, CSR16, NOFF, DEG, NORD, b2,
                                               nullptr, nullptr, X2B,
                                               Ws_rel, Ws_root, SRELP, SROOTP,
                                               XS, 128, 1.f / 1024.f);

    // ---- SAGPooling (score sum + topk + keep-count) ----
    topk_kernel<<<BG, 1024, 0, stream>>>(SRELP, SROOTP, bs, CSR16, NOFF, DEG, KEEP, GATE, CNT);

    // ---- conv3 (gate fused into gemm A-staging) ----
    gemm_kernel<2><<<dim3(NN / 128, 2), 256, 0, stream>>>(X2B, nullptr, GATE, WT + 65536, YB);
    agg_kernel<2><<<BG * 4, 1024, 0, stream>>>(YB, CSR16, NOFF, DEG, NORD, b3,
                                               KEEP, CNT, nullptr,
                                               nullptr, nullptr, nullptr, nullptr,
                                               XS, 256, 1.f / (float)KKEEP);

    // ---- MLP head ----
    mlp_kernel<<<BG, 512, 0, stream>>>(XS, Wl1, bl1, Wl2, bl2, (float*)d_out);
}